// Round 1
// baseline (1523.067 us; speedup 1.0000x reference)
//
#include <hip/hip_runtime.h>
#include <math.h>

#define NN 100000
#define NE 1600000
#define C 128

// ---------------- init: fill max_diff buffer (= d_out) with -inf ----------------
__global__ void init_neginf(float* __restrict__ p, int n) {
    int i = blockIdx.x * blockDim.x + threadIdx.x;
    if (i < n) p[i] = -INFINITY;
}

// float atomic max via int-max (v>=0) / uint-min (v<0). Monotone non-decreasing.
__device__ inline void amaxf(float* a, float v, float cur) {
    if (cur >= v) return;                 // filter: stale-safe (values only grow)
    if (v >= 0.0f) atomicMax((int*)a, __float_as_int(v));
    else           atomicMin((unsigned int*)a, __float_as_uint(v));
}

// ---------------- edge kernel: 32 threads/edge, 4 channels each (float4) --------
__global__ __launch_bounds__(256) void edge_max(
        const float* __restrict__ x, const int* __restrict__ src,
        const int* __restrict__ dst, float* __restrict__ maxdiff) {
    long tid = (long)blockIdx.x * blockDim.x + threadIdx.x;
    int e = (int)(tid >> 5);
    if (e >= NE) return;
    int lane = (int)(tid & 31);
    int s = src[e], d = dst[e];
    int c0 = lane * 4;
    const float4 xd = *(const float4*)(x + (long)d * C + c0);
    const float4 xs = *(const float4*)(x + (long)s * C + c0);
    float4 df;
    df.x = xd.x - xs.x; df.y = xd.y - xs.y;
    df.z = xd.z - xs.z; df.w = xd.w - xs.w;
    float* o = maxdiff + (long)d * C + c0;
    float4 cur = *(const float4*)o;       // racy read, but monotone => safe filter
    amaxf(o + 0, df.x, cur.x);
    amaxf(o + 1, df.y, cur.y);
    amaxf(o + 2, df.z, cur.z);
    amaxf(o + 3, df.w, cur.w);
}

// ---------------- fused (concat + GEMM + bias + relu) ---------------------------
// Block: 256 threads handles 32 nodes x 128 couts. maxdiff lives in d_out rows;
// we stage [x | maxdiff] into LDS first, then overwrite d_out with the result.
#define TN 32
__global__ __launch_bounds__(256) void gemm_relu(
        const float* __restrict__ x, const float* __restrict__ W,
        const float* __restrict__ b, float* __restrict__ out) {
    __shared__ float h[TN][2 * C];        // 32 KB
    const int nb = blockIdx.x * TN;
    const int t  = threadIdx.x;

    // stage 32 rows of h = [x[n], maxdiff[n]] ; fix -inf -> 0
    for (int i = t; i < TN * 2 * C / 4; i += 256) {
        int idx  = i * 4;
        int node = idx / (2 * C);
        int ci   = idx % (2 * C);
        float4 v;
        if (ci < C) {
            v = *(const float4*)(x + (long)(nb + node) * C + ci);
        } else {
            v = *(const float4*)(out + (long)(nb + node) * C + (ci - C));
            if (v.x == -INFINITY) v.x = 0.0f;
            if (v.y == -INFINITY) v.y = 0.0f;
            if (v.z == -INFINITY) v.z = 0.0f;
            if (v.w == -INFINITY) v.w = 0.0f;
        }
        *(float4*)&h[node][ci] = v;
    }
    __syncthreads();

    // thread t: co4 = (t&31)*4 ; nodes n0..n0+3 = (t>>5)*4 ..
    const int co = (t & 31) * 4;
    const int n0 = (t >> 5) * 4;
    float acc[4][4];
    #pragma unroll
    for (int i = 0; i < 4; ++i)
        #pragma unroll
        for (int j = 0; j < 4; ++j) acc[i][j] = 0.0f;

    for (int ci = 0; ci < 2 * C; ++ci) {
        float4 w = *(const float4*)(W + (long)ci * C + co);
        #pragma unroll
        for (int i = 0; i < 4; ++i) {
            float hv = h[n0 + i][ci];
            acc[i][0] = fmaf(hv, w.x, acc[i][0]);
            acc[i][1] = fmaf(hv, w.y, acc[i][1]);
            acc[i][2] = fmaf(hv, w.z, acc[i][2]);
            acc[i][3] = fmaf(hv, w.w, acc[i][3]);
        }
    }

    float4 bias = *(const float4*)(b + co);
    #pragma unroll
    for (int i = 0; i < 4; ++i) {
        float4 r;
        r.x = fmaxf(acc[i][0] + bias.x, 0.0f);
        r.y = fmaxf(acc[i][1] + bias.y, 0.0f);
        r.z = fmaxf(acc[i][2] + bias.z, 0.0f);
        r.w = fmaxf(acc[i][3] + bias.w, 0.0f);
        *(float4*)(out + (long)(nb + n0 + i) * C + co) = r;
    }
}

extern "C" void kernel_launch(void* const* d_in, const int* in_sizes, int n_in,
                              void* d_out, int out_size, void* d_ws, size_t ws_size,
                              hipStream_t stream) {
    const float* x   = (const float*)d_in[0];
    const float* W   = (const float*)d_in[1];
    const float* b   = (const float*)d_in[2];
    const int*   src = (const int*)d_in[3];
    const int*   dst = (const int*)d_in[4];
    float* out = (float*)d_out;

    // 1) init d_out (used as max_diff scratch) to -inf
    {
        int n = NN * C;
        init_neginf<<<(n + 255) / 256, 256, 0, stream>>>(out, n);
    }
    // 2) per-edge max-relative aggregation (atomics into d_out)
    {
        long threads = (long)NE * 32;
        int blocks = (int)((threads + 255) / 256);
        edge_max<<<blocks, 256, 0, stream>>>(x, src, dst, out);
    }
    // 3) fused concat + GEMM + bias + relu (reads maxdiff rows from d_out,
    //    stages to LDS, then overwrites with final output)
    {
        int blocks = (NN + TN - 1) / TN;   // 3125
        gemm_relu<<<blocks, 256, 0, stream>>>(x, W, b, out);
    }
}

// Round 2
// 751.918 us; speedup vs baseline: 2.0256x; 2.0256x over previous
//
#include <hip/hip_runtime.h>
#include <math.h>

#define NN 100000
#define NE 1600000
#define C 128

// ======================= CSR-based path =======================
// d_ws layout: cnt/cursor[NN] | offs[NN+1] | ssrc[NE]   (7.2 MB)

__global__ __launch_bounds__(256) void hist_dst(const int* __restrict__ dst,
                                                int* __restrict__ cnt) {
    int i = blockIdx.x * blockDim.x + threadIdx.x;
    if (i < NE) atomicAdd(&cnt[dst[i]], 1);
}

#define SCAN_T 1024
// cnt_cursor aliases: read as counts, overwritten with running offsets (cursor).
__global__ __launch_bounds__(SCAN_T) void scan_offsets(int* cnt_cursor, int* offs) {
    __shared__ int part[SCAN_T];
    const int t = threadIdx.x;
    const int CH = (NN + SCAN_T - 1) / SCAN_T;   // 98
    int beg = t * CH;
    int end = beg + CH; if (end > NN) end = NN;
    int s = 0;
    for (int i = beg; i < end; ++i) s += cnt_cursor[i];
    part[t] = s;
    __syncthreads();
    for (int off = 1; off < SCAN_T; off <<= 1) {
        int v = part[t];
        int add = (t >= off) ? part[t - off] : 0;
        __syncthreads();
        part[t] = v + add;
        __syncthreads();
    }
    int run = (t == 0) ? 0 : part[t - 1];        // exclusive prefix
    for (int i = beg; i < end; ++i) {
        int c = cnt_cursor[i];                   // read BEFORE overwrite
        offs[i] = run;
        cnt_cursor[i] = run;                     // cursor init
        run += c;
    }
    if (t == SCAN_T - 1) offs[NN] = part[SCAN_T - 1];
}

__global__ __launch_bounds__(256) void scatter_src(const int* __restrict__ src,
                                                   const int* __restrict__ dst,
                                                   int* cursor,
                                                   int* __restrict__ ssrc) {
    int i = blockIdx.x * blockDim.x + threadIdx.x;
    if (i < NE) {
        int p = atomicAdd(&cursor[dst[i]], 1);
        ssrc[p] = src[i];
    }
}

// One wave (64 lanes) per node: lane holds float2 (2 channels).
// max_diff[n] = x[n] - min_{e: dst=n} x[src_e]   (0 if no edges)
__global__ __launch_bounds__(256) void node_min_agg(
        const float* __restrict__ x, const int* __restrict__ offs,
        const int* __restrict__ ssrc, float* __restrict__ maxdiff) {
    int wid  = (blockIdx.x * 256 + threadIdx.x) >> 6;
    int lane = threadIdx.x & 63;
    if (wid >= NN) return;
    const int beg = offs[wid], end = offs[wid + 1];
    const float2* xp = (const float2*)x;
    float2 vmin; vmin.x = INFINITY; vmin.y = INFINITY;
    int i = beg;
    for (; i + 4 <= end; i += 4) {               // 4-deep MLP
        int s0 = ssrc[i], s1 = ssrc[i + 1], s2 = ssrc[i + 2], s3 = ssrc[i + 3];
        float2 a0 = xp[(long)s0 * 64 + lane];
        float2 a1 = xp[(long)s1 * 64 + lane];
        float2 a2 = xp[(long)s2 * 64 + lane];
        float2 a3 = xp[(long)s3 * 64 + lane];
        vmin.x = fminf(vmin.x, fminf(fminf(a0.x, a1.x), fminf(a2.x, a3.x)));
        vmin.y = fminf(vmin.y, fminf(fminf(a0.y, a1.y), fminf(a2.y, a3.y)));
    }
    for (; i < end; ++i) {
        float2 a = xp[(long)ssrc[i] * 64 + lane];
        vmin.x = fminf(vmin.x, a.x);
        vmin.y = fminf(vmin.y, a.y);
    }
    float2 xd = xp[(long)wid * 64 + lane];
    float2 r;
    if (end > beg) { r.x = xd.x - vmin.x; r.y = xd.y - vmin.y; }
    else           { r.x = 0.0f;         r.y = 0.0f; }
    ((float2*)maxdiff)[(long)wid * 64 + lane] = r;
}

// ======================= fallback atomic path =======================
__global__ void init_neginf(float* __restrict__ p, int n) {
    int i = blockIdx.x * blockDim.x + threadIdx.x;
    if (i < n) p[i] = -INFINITY;
}

__device__ inline void amaxf(float* a, float v, float cur) {
    if (cur >= v) return;
    if (v >= 0.0f) atomicMax((int*)a, __float_as_int(v));
    else           atomicMin((unsigned int*)a, __float_as_uint(v));
}

__global__ __launch_bounds__(256) void edge_max(
        const float* __restrict__ x, const int* __restrict__ src,
        const int* __restrict__ dst, float* __restrict__ maxdiff) {
    long tid = (long)blockIdx.x * blockDim.x + threadIdx.x;
    int e = (int)(tid >> 5);
    if (e >= NE) return;
    int lane = (int)(tid & 31);
    int s = src[e], d = dst[e];
    int c0 = lane * 4;
    const float4 xd = *(const float4*)(x + (long)d * C + c0);
    const float4 xs = *(const float4*)(x + (long)s * C + c0);
    float4 df;
    df.x = xd.x - xs.x; df.y = xd.y - xs.y;
    df.z = xd.z - xs.z; df.w = xd.w - xs.w;
    float* o = maxdiff + (long)d * C + c0;
    float4 cur = *(const float4*)o;
    amaxf(o + 0, df.x, cur.x);
    amaxf(o + 1, df.y, cur.y);
    amaxf(o + 2, df.z, cur.z);
    amaxf(o + 3, df.w, cur.w);
}

// ======================= fused concat + GEMM + bias + relu =======================
#define TN 32
__global__ __launch_bounds__(256) void gemm_relu(
        const float* __restrict__ x, const float* __restrict__ W,
        const float* __restrict__ b, float* __restrict__ out) {
    __shared__ float h[TN][2 * C];        // 32 KB
    const int nb = blockIdx.x * TN;
    const int t  = threadIdx.x;

    for (int i = t; i < TN * 2 * C / 4; i += 256) {
        int idx  = i * 4;
        int node = idx / (2 * C);
        int ci   = idx % (2 * C);
        float4 v;
        if (ci < C) {
            v = *(const float4*)(x + (long)(nb + node) * C + ci);
        } else {
            v = *(const float4*)(out + (long)(nb + node) * C + (ci - C));
            if (v.x == -INFINITY) v.x = 0.0f;   // harmless on CSR path
            if (v.y == -INFINITY) v.y = 0.0f;
            if (v.z == -INFINITY) v.z = 0.0f;
            if (v.w == -INFINITY) v.w = 0.0f;
        }
        *(float4*)&h[node][ci] = v;
    }
    __syncthreads();

    const int co = (t & 31) * 4;
    const int n0 = (t >> 5) * 4;
    float acc[4][4];
    #pragma unroll
    for (int i = 0; i < 4; ++i)
        #pragma unroll
        for (int j = 0; j < 4; ++j) acc[i][j] = 0.0f;

    for (int ci = 0; ci < 2 * C; ++ci) {
        float4 w = *(const float4*)(W + (long)ci * C + co);
        #pragma unroll
        for (int i = 0; i < 4; ++i) {
            float hv = h[n0 + i][ci];
            acc[i][0] = fmaf(hv, w.x, acc[i][0]);
            acc[i][1] = fmaf(hv, w.y, acc[i][1]);
            acc[i][2] = fmaf(hv, w.z, acc[i][2]);
            acc[i][3] = fmaf(hv, w.w, acc[i][3]);
        }
    }

    float4 bias = *(const float4*)(b + co);
    #pragma unroll
    for (int i = 0; i < 4; ++i) {
        float4 r;
        r.x = fmaxf(acc[i][0] + bias.x, 0.0f);
        r.y = fmaxf(acc[i][1] + bias.y, 0.0f);
        r.z = fmaxf(acc[i][2] + bias.z, 0.0f);
        r.w = fmaxf(acc[i][3] + bias.w, 0.0f);
        *(float4*)(out + (long)(nb + n0 + i) * C + co) = r;
    }
}

extern "C" void kernel_launch(void* const* d_in, const int* in_sizes, int n_in,
                              void* d_out, int out_size, void* d_ws, size_t ws_size,
                              hipStream_t stream) {
    const float* x   = (const float*)d_in[0];
    const float* W   = (const float*)d_in[1];
    const float* b   = (const float*)d_in[2];
    const int*   src = (const int*)d_in[3];
    const int*   dst = (const int*)d_in[4];
    float* out = (float*)d_out;

    const size_t ws_need = (size_t)(2 * NN + 1 + NE) * 4;   // 7.2 MB

    if (ws_size >= ws_need) {
        int* cnt_cursor = (int*)d_ws;            // [NN]
        int* offs       = (int*)d_ws + NN;       // [NN+1]
        int* ssrc       = (int*)d_ws + 2 * NN + 1; // [NE]

        hipMemsetAsync(cnt_cursor, 0, (size_t)NN * 4, stream);
        hist_dst<<<(NE + 255) / 256, 256, 0, stream>>>(dst, cnt_cursor);
        scan_offsets<<<1, SCAN_T, 0, stream>>>(cnt_cursor, offs);
        scatter_src<<<(NE + 255) / 256, 256, 0, stream>>>(src, dst, cnt_cursor, ssrc);
        node_min_agg<<<NN / 4, 256, 0, stream>>>(x, offs, ssrc, out);
    } else {
        // fallback: atomic-max path (round-1)
        int n = NN * C;
        init_neginf<<<(n + 255) / 256, 256, 0, stream>>>(out, n);
        long threads = (long)NE * 32;
        edge_max<<<(int)((threads + 255) / 256), 256, 0, stream>>>(x, src, dst, out);
    }

    gemm_relu<<<(NN + TN - 1) / TN, 256, 0, stream>>>(x, W, b, out);
}

// Round 3
// 538.029 us; speedup vs baseline: 2.8308x; 1.3975x over previous
//
#include <hip/hip_runtime.h>
#include <math.h>

#define NN 100000
#define NE 1600000
#define C 128
#define NB ((NN + 2047) / 2048)   // 49 scan blocks

// ======================= CSR build =======================
// d_ws layout: cnt/cursor[NN] | offs[NN+1] | ssrc[NE] | blocksums[64] | blockbase[64]

__global__ __launch_bounds__(256) void hist_dst(const int* __restrict__ dst,
                                                int* __restrict__ cnt) {
    int i = blockIdx.x * blockDim.x + threadIdx.x;
    if (i < NE) atomicAdd(&cnt[dst[i]], 1);
}

// phase 1: per-block (2048 elems) exclusive scan into offs, block sum out
__global__ __launch_bounds__(256) void scan_partial(const int* __restrict__ cnt,
                                                    int* __restrict__ offs,
                                                    int* __restrict__ blocksums) {
    __shared__ int ts[256];
    const int t = threadIdx.x;
    const int base = blockIdx.x * 2048 + t * 8;
    int c[8];
    int s = 0;
    #pragma unroll
    for (int j = 0; j < 8; ++j) {
        int i = base + j;
        c[j] = (i < NN) ? cnt[i] : 0;
        s += c[j];
    }
    ts[t] = s;
    __syncthreads();
    for (int off = 1; off < 256; off <<= 1) {   // Hillis-Steele inclusive
        int add = (t >= off) ? ts[t - off] : 0;
        __syncthreads();
        ts[t] += add;
        __syncthreads();
    }
    int run = (t == 0) ? 0 : ts[t - 1];
    #pragma unroll
    for (int j = 0; j < 8; ++j) {
        int i = base + j;
        if (i < NN) offs[i] = run;
        run += c[j];
    }
    if (t == 255) blocksums[blockIdx.x] = ts[255];
}

// phase 2: one wave scans the NB block sums (NB=49 <= 64)
__global__ __launch_bounds__(64) void scan_blocksums(const int* __restrict__ blocksums,
                                                     int* __restrict__ blockbase) {
    int lane = threadIdx.x;
    int v = (lane < NB) ? blocksums[lane] : 0;
    int incl = v;
    #pragma unroll
    for (int off = 1; off < 64; off <<= 1) {
        int n = __shfl_up(incl, off, 64);
        if (lane >= off) incl += n;
    }
    if (lane < NB) blockbase[lane] = incl - v;
}

// phase 3: fold in block bases; init cursor (aliases cnt, dead by now)
__global__ __launch_bounds__(256) void add_base_init_cursor(
        int* __restrict__ offs, const int* __restrict__ blockbase,
        int* __restrict__ cursor) {
    int i = blockIdx.x * 256 + threadIdx.x;
    if (i < NN) {
        int v = offs[i] + blockbase[i >> 11];
        offs[i] = v;
        cursor[i] = v;
    }
    if (i == 0) offs[NN] = NE;
}

__global__ __launch_bounds__(256) void scatter_src(const int* __restrict__ src,
                                                   const int* __restrict__ dst,
                                                   int* cursor,
                                                   int* __restrict__ ssrc) {
    int i = blockIdx.x * blockDim.x + threadIdx.x;
    if (i < NE) {
        int p = atomicAdd(&cursor[dst[i]], 1);
        ssrc[p] = src[i];
    }
}

// One wave (64 lanes) per node: lane holds float2 (2 channels).
// max_diff[n] = x[n] - min_{e: dst=n} x[src_e]   (0 if no edges)
__global__ __launch_bounds__(256) void node_min_agg(
        const float* __restrict__ x, const int* __restrict__ offs,
        const int* __restrict__ ssrc, float* __restrict__ maxdiff) {
    int wid  = (blockIdx.x * 256 + threadIdx.x) >> 6;
    int lane = threadIdx.x & 63;
    if (wid >= NN) return;
    const int beg = offs[wid], end = offs[wid + 1];
    const float2* xp = (const float2*)x;
    float2 vmin; vmin.x = INFINITY; vmin.y = INFINITY;
    int i = beg;
    for (; i + 4 <= end; i += 4) {
        int s0 = ssrc[i], s1 = ssrc[i + 1], s2 = ssrc[i + 2], s3 = ssrc[i + 3];
        float2 a0 = xp[(long)s0 * 64 + lane];
        float2 a1 = xp[(long)s1 * 64 + lane];
        float2 a2 = xp[(long)s2 * 64 + lane];
        float2 a3 = xp[(long)s3 * 64 + lane];
        vmin.x = fminf(vmin.x, fminf(fminf(a0.x, a1.x), fminf(a2.x, a3.x)));
        vmin.y = fminf(vmin.y, fminf(fminf(a0.y, a1.y), fminf(a2.y, a3.y)));
    }
    for (; i < end; ++i) {
        float2 a = xp[(long)ssrc[i] * 64 + lane];
        vmin.x = fminf(vmin.x, a.x);
        vmin.y = fminf(vmin.y, a.y);
    }
    float2 xd = xp[(long)wid * 64 + lane];
    float2 r;
    if (end > beg) { r.x = xd.x - vmin.x; r.y = xd.y - vmin.y; }
    else           { r.x = 0.0f;         r.y = 0.0f; }
    ((float2*)maxdiff)[(long)wid * 64 + lane] = r;
}

// ======================= fallback atomic path =======================
__global__ void init_neginf(float* __restrict__ p, int n) {
    int i = blockIdx.x * blockDim.x + threadIdx.x;
    if (i < n) p[i] = -INFINITY;
}

__device__ inline void amaxf(float* a, float v, float cur) {
    if (cur >= v) return;
    if (v >= 0.0f) atomicMax((int*)a, __float_as_int(v));
    else           atomicMin((unsigned int*)a, __float_as_uint(v));
}

__global__ __launch_bounds__(256) void edge_max(
        const float* __restrict__ x, const int* __restrict__ src,
        const int* __restrict__ dst, float* __restrict__ maxdiff) {
    long tid = (long)blockIdx.x * blockDim.x + threadIdx.x;
    int e = (int)(tid >> 5);
    if (e >= NE) return;
    int lane = (int)(tid & 31);
    int s = src[e], d = dst[e];
    int c0 = lane * 4;
    const float4 xd = *(const float4*)(x + (long)d * C + c0);
    const float4 xs = *(const float4*)(x + (long)s * C + c0);
    float4 df;
    df.x = xd.x - xs.x; df.y = xd.y - xs.y;
    df.z = xd.z - xs.z; df.w = xd.w - xs.w;
    float* o = maxdiff + (long)d * C + c0;
    float4 cur = *(const float4*)o;
    amaxf(o + 0, df.x, cur.x);
    amaxf(o + 1, df.y, cur.y);
    amaxf(o + 2, df.z, cur.z);
    amaxf(o + 3, df.w, cur.w);
}

// ======================= fused concat + GEMM + bias + relu =======================
#define TN 32
__global__ __launch_bounds__(256) void gemm_relu(
        const float* __restrict__ x, const float* __restrict__ W,
        const float* __restrict__ b, float* __restrict__ out) {
    __shared__ float h[TN][2 * C];        // 32 KB
    const int nb = blockIdx.x * TN;
    const int t  = threadIdx.x;

    for (int i = t; i < TN * 2 * C / 4; i += 256) {
        int idx  = i * 4;
        int node = idx / (2 * C);
        int ci   = idx % (2 * C);
        float4 v;
        if (ci < C) {
            v = *(const float4*)(x + (long)(nb + node) * C + ci);
        } else {
            v = *(const float4*)(out + (long)(nb + node) * C + (ci - C));
            if (v.x == -INFINITY) v.x = 0.0f;   // harmless on CSR path
            if (v.y == -INFINITY) v.y = 0.0f;
            if (v.z == -INFINITY) v.z = 0.0f;
            if (v.w == -INFINITY) v.w = 0.0f;
        }
        *(float4*)&h[node][ci] = v;
    }
    __syncthreads();

    const int co = (t & 31) * 4;
    const int n0 = (t >> 5) * 4;
    float acc[4][4];
    #pragma unroll
    for (int i = 0; i < 4; ++i)
        #pragma unroll
        for (int j = 0; j < 4; ++j) acc[i][j] = 0.0f;

    for (int ci = 0; ci < 2 * C; ++ci) {
        float4 w = *(const float4*)(W + (long)ci * C + co);
        #pragma unroll
        for (int i = 0; i < 4; ++i) {
            float hv = h[n0 + i][ci];
            acc[i][0] = fmaf(hv, w.x, acc[i][0]);
            acc[i][1] = fmaf(hv, w.y, acc[i][1]);
            acc[i][2] = fmaf(hv, w.z, acc[i][2]);
            acc[i][3] = fmaf(hv, w.w, acc[i][3]);
        }
    }

    float4 bias = *(const float4*)(b + co);
    #pragma unroll
    for (int i = 0; i < 4; ++i) {
        float4 r;
        r.x = fmaxf(acc[i][0] + bias.x, 0.0f);
        r.y = fmaxf(acc[i][1] + bias.y, 0.0f);
        r.z = fmaxf(acc[i][2] + bias.z, 0.0f);
        r.w = fmaxf(acc[i][3] + bias.w, 0.0f);
        *(float4*)(out + (long)(nb + n0 + i) * C + co) = r;
    }
}

extern "C" void kernel_launch(void* const* d_in, const int* in_sizes, int n_in,
                              void* d_out, int out_size, void* d_ws, size_t ws_size,
                              hipStream_t stream) {
    const float* x   = (const float*)d_in[0];
    const float* W   = (const float*)d_in[1];
    const float* b   = (const float*)d_in[2];
    const int*   src = (const int*)d_in[3];
    const int*   dst = (const int*)d_in[4];
    float* out = (float*)d_out;

    const size_t ws_need = (size_t)(2 * NN + 1 + NE + 128) * 4;

    if (ws_size >= ws_need) {
        int* cnt_cursor = (int*)d_ws;                  // [NN]
        int* offs       = (int*)d_ws + NN;             // [NN+1]
        int* ssrc       = (int*)d_ws + 2 * NN + 1;     // [NE]
        int* blocksums  = (int*)d_ws + 2 * NN + 1 + NE;      // [64]
        int* blockbase  = (int*)d_ws + 2 * NN + 1 + NE + 64; // [64]

        hipMemsetAsync(cnt_cursor, 0, (size_t)NN * 4, stream);
        hist_dst<<<(NE + 255) / 256, 256, 0, stream>>>(dst, cnt_cursor);
        scan_partial<<<NB, 256, 0, stream>>>(cnt_cursor, offs, blocksums);
        scan_blocksums<<<1, 64, 0, stream>>>(blocksums, blockbase);
        add_base_init_cursor<<<(NN + 255) / 256, 256, 0, stream>>>(offs, blockbase, cnt_cursor);
        scatter_src<<<(NE + 255) / 256, 256, 0, stream>>>(src, dst, cnt_cursor, ssrc);
        node_min_agg<<<NN / 4, 256, 0, stream>>>(x, offs, ssrc, out);
    } else {
        // fallback: atomic-max path
        int n = NN * C;
        init_neginf<<<(n + 255) / 256, 256, 0, stream>>>(out, n);
        long threads = (long)NE * 32;
        edge_max<<<(int)((threads + 255) / 256), 256, 0, stream>>>(x, src, dst, out);
    }

    gemm_relu<<<(NN + TN - 1) / TN, 256, 0, stream>>>(x, W, b, out);
}

// Round 4
// 459.967 us; speedup vs baseline: 3.3113x; 1.1697x over previous
//
#include <hip/hip_runtime.h>
#include <math.h>

#define NN 100000
#define NE 1600000
#define C 128
#define NB ((NN + 2047) / 2048)   // 49 scan blocks

typedef __attribute__((ext_vector_type(8))) short   bf16x8;
typedef __attribute__((ext_vector_type(4))) float   f32x4;
typedef unsigned short ushort_t;
typedef unsigned int   uint_t;

__device__ inline ushort_t f2bf(float f) {   // RTNE float -> bf16 bits
    union { float f; uint_t u; } a; a.f = f;
    uint_t r = a.u + 0x7fff + ((a.u >> 16) & 1);
    return (ushort_t)(r >> 16);
}

// ======================= CSR build =======================
__global__ __launch_bounds__(256) void hist_dst(const int* __restrict__ dst,
                                                int* __restrict__ cnt) {
    int i = blockIdx.x * blockDim.x + threadIdx.x;
    if (i < NE) atomicAdd(&cnt[dst[i]], 1);
}

__global__ __launch_bounds__(256) void scan_partial(const int* __restrict__ cnt,
                                                    int* __restrict__ offs,
                                                    int* __restrict__ blocksums) {
    __shared__ int ts[256];
    const int t = threadIdx.x;
    const int base = blockIdx.x * 2048 + t * 8;
    int c[8];
    int s = 0;
    #pragma unroll
    for (int j = 0; j < 8; ++j) {
        int i = base + j;
        c[j] = (i < NN) ? cnt[i] : 0;
        s += c[j];
    }
    ts[t] = s;
    __syncthreads();
    for (int off = 1; off < 256; off <<= 1) {
        int add = (t >= off) ? ts[t - off] : 0;
        __syncthreads();
        ts[t] += add;
        __syncthreads();
    }
    int run = (t == 0) ? 0 : ts[t - 1];
    #pragma unroll
    for (int j = 0; j < 8; ++j) {
        int i = base + j;
        if (i < NN) offs[i] = run;
        run += c[j];
    }
    if (t == 255) blocksums[blockIdx.x] = ts[255];
}

__global__ __launch_bounds__(64) void scan_blocksums(const int* __restrict__ blocksums,
                                                     int* __restrict__ blockbase) {
    int lane = threadIdx.x;
    int v = (lane < NB) ? blocksums[lane] : 0;
    int incl = v;
    #pragma unroll
    for (int off = 1; off < 64; off <<= 1) {
        int n = __shfl_up(incl, off, 64);
        if (lane >= off) incl += n;
    }
    if (lane < NB) blockbase[lane] = incl - v;
}

__global__ __launch_bounds__(256) void add_base_init_cursor(
        int* __restrict__ offs, const int* __restrict__ blockbase,
        int* __restrict__ cursor) {
    int i = blockIdx.x * 256 + threadIdx.x;
    if (i < NN) {
        int v = offs[i] + blockbase[i >> 11];
        offs[i] = v;
        cursor[i] = v;
    }
    if (i == 0) offs[NN] = NE;
}

__global__ __launch_bounds__(256) void scatter_src(const int* __restrict__ src,
                                                   const int* __restrict__ dst,
                                                   int* cursor,
                                                   int* __restrict__ ssrc) {
    int i = blockIdx.x * blockDim.x + threadIdx.x;
    if (i < NE) {
        int p = atomicAdd(&cursor[dst[i]], 1);
        ssrc[p] = src[i];
    }
}

// ======================= bf16 path =======================
// xh layout: [NN][256] bf16; cols 0..127 = bf16(x), cols 128..255 = bf16(maxdiff)

__global__ __launch_bounds__(256) void prep_xh(const float* __restrict__ x,
                                               ushort_t* __restrict__ xh) {
    int i = blockIdx.x * 256 + threadIdx.x;          // one thread per 8 floats
    if (i >= NN * C / 8) return;
    int node = i >> 4;                               // 16 octs per row
    int c0   = (i & 15) * 8;
    const float4* xp = (const float4*)(x + (long)i * 8);
    float4 v0 = xp[0], v1 = xp[1];
    ushort_t o[8] = { f2bf(v0.x), f2bf(v0.y), f2bf(v0.z), f2bf(v0.w),
                      f2bf(v1.x), f2bf(v1.y), f2bf(v1.z), f2bf(v1.w) };
    *(bf16x8*)(xh + (long)node * 256 + c0) = *(bf16x8*)o;
}

// W fp32 [256][128] -> Wt bf16 [128][256]
__global__ __launch_bounds__(256) void conv_w(const float* __restrict__ W,
                                              ushort_t* __restrict__ Wt) {
    int i = blockIdx.x * 256 + threadIdx.x;
    if (i >= 2 * C * C) return;
    int k = i >> 7, n = i & 127;
    Wt[n * 256 + k] = f2bf(W[i]);
}

// one wave per node; lane handles 2 channels (uint = 2 bf16)
__global__ __launch_bounds__(256) void node_min_bf16(
        const int* __restrict__ offs, const int* __restrict__ ssrc,
        ushort_t* __restrict__ xh) {
    int wid  = (blockIdx.x * 256 + threadIdx.x) >> 6;
    int lane = threadIdx.x & 63;
    if (wid >= NN) return;
    const int beg = offs[wid], end = offs[wid + 1];
    const uint_t* xp = (const uint_t*)xh;            // row = 128 uints
    float m0 = INFINITY, m1 = INFINITY;
    int i = beg;
    for (; i + 4 <= end; i += 4) {
        uint_t a0 = xp[(long)ssrc[i]     * 128 + lane];
        uint_t a1 = xp[(long)ssrc[i + 1] * 128 + lane];
        uint_t a2 = xp[(long)ssrc[i + 2] * 128 + lane];
        uint_t a3 = xp[(long)ssrc[i + 3] * 128 + lane];
        m0 = fminf(m0, fminf(fminf(__uint_as_float(a0 << 16), __uint_as_float(a1 << 16)),
                             fminf(__uint_as_float(a2 << 16), __uint_as_float(a3 << 16))));
        m1 = fminf(m1, fminf(fminf(__uint_as_float(a0 & 0xffff0000u), __uint_as_float(a1 & 0xffff0000u)),
                             fminf(__uint_as_float(a2 & 0xffff0000u), __uint_as_float(a3 & 0xffff0000u))));
    }
    for (; i < end; ++i) {
        uint_t a = xp[(long)ssrc[i] * 128 + lane];
        m0 = fminf(m0, __uint_as_float(a << 16));
        m1 = fminf(m1, __uint_as_float(a & 0xffff0000u));
    }
    uint_t xd = xp[(long)wid * 128 + lane];
    float d0 = 0.0f, d1 = 0.0f;
    if (end > beg) {
        d0 = __uint_as_float(xd << 16)         - m0;
        d1 = __uint_as_float(xd & 0xffff0000u) - m1;
    }
    uint_t packed = (uint_t)f2bf(d0) | ((uint_t)f2bf(d1) << 16);
    ((uint_t*)xh)[(long)wid * 128 + 64 + lane] = packed;
}

// MFMA GEMM: out[N,128] = relu(h[N,256] @ W + b), h/Wt in bf16, acc fp32
__global__ __launch_bounds__(256) void gemm_mfma(
        const ushort_t* __restrict__ xh, const ushort_t* __restrict__ Wt,
        const float* __restrict__ b, float* __restrict__ out) {
    const int w  = threadIdx.x >> 6;
    const int l  = threadIdx.x & 63;
    const int m0 = blockIdx.x * 64 + w * 16;
    int arow = m0 + (l & 15);
    if (arow >= NN) arow = NN - 1;                   // clamp (stores guarded)
    const int kb = (l >> 4) * 8;

    f32x4 acc[8];
    #pragma unroll
    for (int n = 0; n < 8; ++n) acc[n] = (f32x4){0.f, 0.f, 0.f, 0.f};

    const ushort_t* ap    = xh + (long)arow * 256 + kb;
    const ushort_t* wbase = Wt + (l & 15) * 256 + kb;

    #pragma unroll
    for (int k0 = 0; k0 < 256; k0 += 32) {
        bf16x8 a = *(const bf16x8*)(ap + k0);
        #pragma unroll
        for (int n = 0; n < 8; ++n) {
            bf16x8 bb = *(const bf16x8*)(wbase + n * 16 * 256 + k0);
            acc[n] = __builtin_amdgcn_mfma_f32_16x16x32_bf16(a, bb, acc[n], 0, 0, 0);
        }
    }

    const int colb  = l & 15;
    const int rbase = m0 + ((l >> 4) << 2);
    #pragma unroll
    for (int n = 0; n < 8; ++n) {
        int col = n * 16 + colb;
        float bv = b[col];
        #pragma unroll
        for (int j = 0; j < 4; ++j) {
            int r = rbase + j;
            if (r < NN) out[(long)r * 128 + col] = fmaxf(acc[n][j] + bv, 0.0f);
        }
    }
}

// ======================= fp32 fallback (round-3) =======================
__global__ __launch_bounds__(256) void node_min_agg(
        const float* __restrict__ x, const int* __restrict__ offs,
        const int* __restrict__ ssrc, float* __restrict__ maxdiff) {
    int wid  = (blockIdx.x * 256 + threadIdx.x) >> 6;
    int lane = threadIdx.x & 63;
    if (wid >= NN) return;
    const int beg = offs[wid], end = offs[wid + 1];
    const float2* xp = (const float2*)x;
    float2 vmin; vmin.x = INFINITY; vmin.y = INFINITY;
    int i = beg;
    for (; i + 4 <= end; i += 4) {
        int s0 = ssrc[i], s1 = ssrc[i + 1], s2 = ssrc[i + 2], s3 = ssrc[i + 3];
        float2 a0 = xp[(long)s0 * 64 + lane];
        float2 a1 = xp[(long)s1 * 64 + lane];
        float2 a2 = xp[(long)s2 * 64 + lane];
        float2 a3 = xp[(long)s3 * 64 + lane];
        vmin.x = fminf(vmin.x, fminf(fminf(a0.x, a1.x), fminf(a2.x, a3.x)));
        vmin.y = fminf(vmin.y, fminf(fminf(a0.y, a1.y), fminf(a2.y, a3.y)));
    }
    for (; i < end; ++i) {
        float2 a = xp[(long)ssrc[i] * 64 + lane];
        vmin.x = fminf(vmin.x, a.x);
        vmin.y = fminf(vmin.y, a.y);
    }
    float2 xd = xp[(long)wid * 64 + lane];
    float2 r;
    if (end > beg) { r.x = xd.x - vmin.x; r.y = xd.y - vmin.y; }
    else           { r.x = 0.0f;         r.y = 0.0f; }
    ((float2*)maxdiff)[(long)wid * 64 + lane] = r;
}

__global__ void init_neginf(float* __restrict__ p, int n) {
    int i = blockIdx.x * blockDim.x + threadIdx.x;
    if (i < n) p[i] = -INFINITY;
}

__device__ inline void amaxf(float* a, float v, float cur) {
    if (cur >= v) return;
    if (v >= 0.0f) atomicMax((int*)a, __float_as_int(v));
    else           atomicMin((unsigned int*)a, __float_as_uint(v));
}

__global__ __launch_bounds__(256) void edge_max(
        const float* __restrict__ x, const int* __restrict__ src,
        const int* __restrict__ dst, float* __restrict__ maxdiff) {
    long tid = (long)blockIdx.x * blockDim.x + threadIdx.x;
    int e = (int)(tid >> 5);
    if (e >= NE) return;
    int lane = (int)(tid & 31);
    int s = src[e], d = dst[e];
    int c0 = lane * 4;
    const float4 xd = *(const float4*)(x + (long)d * C + c0);
    const float4 xs = *(const float4*)(x + (long)s * C + c0);
    float4 df;
    df.x = xd.x - xs.x; df.y = xd.y - xs.y;
    df.z = xd.z - xs.z; df.w = xd.w - xs.w;
    float* o = maxdiff + (long)d * C + c0;
    float4 cur = *(const float4*)o;
    amaxf(o + 0, df.x, cur.x);
    amaxf(o + 1, df.y, cur.y);
    amaxf(o + 2, df.z, cur.z);
    amaxf(o + 3, df.w, cur.w);
}

#define TN 32
__global__ __launch_bounds__(256) void gemm_relu(
        const float* __restrict__ x, const float* __restrict__ W,
        const float* __restrict__ b, float* __restrict__ out) {
    __shared__ float h[TN][2 * C];
    const int nb = blockIdx.x * TN;
    const int t  = threadIdx.x;
    for (int i = t; i < TN * 2 * C / 4; i += 256) {
        int idx  = i * 4;
        int node = idx / (2 * C);
        int ci   = idx % (2 * C);
        float4 v;
        if (ci < C) {
            v = *(const float4*)(x + (long)(nb + node) * C + ci);
        } else {
            v = *(const float4*)(out + (long)(nb + node) * C + (ci - C));
            if (v.x == -INFINITY) v.x = 0.0f;
            if (v.y == -INFINITY) v.y = 0.0f;
            if (v.z == -INFINITY) v.z = 0.0f;
            if (v.w == -INFINITY) v.w = 0.0f;
        }
        *(float4*)&h[node][ci] = v;
    }
    __syncthreads();
    const int co = (t & 31) * 4;
    const int n0 = (t >> 5) * 4;
    float acc[4][4];
    #pragma unroll
    for (int i = 0; i < 4; ++i)
        #pragma unroll
        for (int j = 0; j < 4; ++j) acc[i][j] = 0.0f;
    for (int ci = 0; ci < 2 * C; ++ci) {
        float4 w = *(const float4*)(W + (long)ci * C + co);
        #pragma unroll
        for (int i = 0; i < 4; ++i) {
            float hv = h[n0 + i][ci];
            acc[i][0] = fmaf(hv, w.x, acc[i][0]);
            acc[i][1] = fmaf(hv, w.y, acc[i][1]);
            acc[i][2] = fmaf(hv, w.z, acc[i][2]);
            acc[i][3] = fmaf(hv, w.w, acc[i][3]);
        }
    }
    float4 bias = *(const float4*)(b + co);
    #pragma unroll
    for (int i = 0; i < 4; ++i) {
        float4 r;
        r.x = fmaxf(acc[i][0] + bias.x, 0.0f);
        r.y = fmaxf(acc[i][1] + bias.y, 0.0f);
        r.z = fmaxf(acc[i][2] + bias.z, 0.0f);
        r.w = fmaxf(acc[i][3] + bias.w, 0.0f);
        *(float4*)(out + (long)(nb + n0 + i) * C + co) = r;
    }
}

extern "C" void kernel_launch(void* const* d_in, const int* in_sizes, int n_in,
                              void* d_out, int out_size, void* d_ws, size_t ws_size,
                              hipStream_t stream) {
    const float* x   = (const float*)d_in[0];
    const float* W   = (const float*)d_in[1];
    const float* b   = (const float*)d_in[2];
    const int*   src = (const int*)d_in[3];
    const int*   dst = (const int*)d_in[4];
    float* out = (float*)d_out;

    const size_t n_ints   = (size_t)(2 * NN + 1 + NE + 128);
    const size_t csr_b    = ((n_ints * 4) + 63) & ~(size_t)63;      // 7.20 MB
    const size_t xh_b     = (size_t)NN * 256 * 2;                   // 51.2 MB
    const size_t wt_b     = (size_t)2 * C * C * 2;                  // 64 KB
    const size_t need_bf  = csr_b + xh_b + wt_b;
    const size_t need_csr = n_ints * 4;

    if (ws_size >= need_csr) {
        int* cnt_cursor = (int*)d_ws;
        int* offs       = (int*)d_ws + NN;
        int* ssrc       = (int*)d_ws + 2 * NN + 1;
        int* blocksums  = (int*)d_ws + 2 * NN + 1 + NE;
        int* blockbase  = (int*)d_ws + 2 * NN + 1 + NE + 64;

        hipMemsetAsync(cnt_cursor, 0, (size_t)NN * 4, stream);
        hist_dst<<<(NE + 255) / 256, 256, 0, stream>>>(dst, cnt_cursor);
        scan_partial<<<NB, 256, 0, stream>>>(cnt_cursor, offs, blocksums);
        scan_blocksums<<<1, 64, 0, stream>>>(blocksums, blockbase);
        add_base_init_cursor<<<(NN + 255) / 256, 256, 0, stream>>>(offs, blockbase, cnt_cursor);
        scatter_src<<<(NE + 255) / 256, 256, 0, stream>>>(src, dst, cnt_cursor, ssrc);

        if (ws_size >= need_bf) {
            ushort_t* xh = (ushort_t*)((char*)d_ws + csr_b);
            ushort_t* Wt = (ushort_t*)((char*)d_ws + csr_b + xh_b);
            prep_xh<<<(NN * C / 8 + 255) / 256, 256, 0, stream>>>(x, xh);
            conv_w<<<(2 * C * C + 255) / 256, 256, 0, stream>>>(W, Wt);
            node_min_bf16<<<NN / 4, 256, 0, stream>>>(offs, ssrc, xh);
            gemm_mfma<<<(NN + 63) / 64, 256, 0, stream>>>(xh, Wt, b, out);
        } else {
            node_min_agg<<<NN / 4, 256, 0, stream>>>(x, offs, ssrc, out);
            gemm_relu<<<(NN + TN - 1) / TN, 256, 0, stream>>>(x, W, b, out);
        }
    } else {
        int n = NN * C;
        init_neginf<<<(n + 255) / 256, 256, 0, stream>>>(out, n);
        long threads = (long)NE * 32;
        edge_max<<<(int)((threads + 255) / 256), 256, 0, stream>>>(x, src, dst, out);
        gemm_relu<<<(NN + TN - 1) / TN, 256, 0, stream>>>(x, W, b, out);
    }
}

// Round 5
// 298.702 us; speedup vs baseline: 5.0989x; 1.5399x over previous
//
#include <hip/hip_runtime.h>
#include <math.h>

#define NN 100000
#define NE 1600000
#define C 128

#define TS 4096                       // edges per sort tile
#define NT ((NE + TS - 1) / TS)       // 391 tiles
#define BUK ((NN + 511) >> 9)         // 196 buckets of 512 nodes
#define NSC (BUK * NT)                // 76636 scan elements
#define NBS ((NSC + 2047) / 2048)     // 38 scan blocks (<=64)

typedef __attribute__((ext_vector_type(8))) short   bf16x8;
typedef __attribute__((ext_vector_type(4))) float   f32x4;
typedef unsigned short ushort_t;
typedef unsigned int   uint_t;

__device__ inline ushort_t f2bf(float f) {   // RTNE float -> bf16 bits
    union { float f; uint_t u; } a; a.f = f;
    uint_t r = a.u + 0x7fff + ((a.u >> 16) & 1);
    return (ushort_t)(r >> 16);
}

// ======================= sort: P1 tile histogram =======================
__global__ __launch_bounds__(256) void p1_hist(const int* __restrict__ dst,
                                               int* __restrict__ tileHistT) {
    __shared__ int h[BUK];
    const int t = threadIdx.x, tile = blockIdx.x;
    for (int i = t; i < BUK; i += 256) h[i] = 0;
    __syncthreads();
    const int base = tile * TS;
    for (int i = t; i < TS; i += 256) {
        int e = base + i;
        if (e < NE) atomicAdd(&h[dst[e] >> 9], 1);
    }
    __syncthreads();
    for (int i = t; i < BUK; i += 256) tileHistT[i * NT + tile] = h[i];
}

// ======================= generic 3-kernel scan =======================
__global__ __launch_bounds__(256) void scan_partial(const int* __restrict__ in,
                                                    int* __restrict__ out,
                                                    int* __restrict__ blocksums,
                                                    int n) {
    __shared__ int ts[256];
    const int t = threadIdx.x;
    const int base = blockIdx.x * 2048 + t * 8;
    int c[8];
    int s = 0;
    #pragma unroll
    for (int j = 0; j < 8; ++j) {
        int i = base + j;
        c[j] = (i < n) ? in[i] : 0;
        s += c[j];
    }
    ts[t] = s;
    __syncthreads();
    for (int off = 1; off < 256; off <<= 1) {
        int add = (t >= off) ? ts[t - off] : 0;
        __syncthreads();
        ts[t] += add;
        __syncthreads();
    }
    int run = (t == 0) ? 0 : ts[t - 1];
    #pragma unroll
    for (int j = 0; j < 8; ++j) {
        int i = base + j;
        if (i < n) out[i] = run;
        run += c[j];
    }
    if (t == 255) blocksums[blockIdx.x] = ts[255];
}

__global__ __launch_bounds__(64) void scan_blocksums(const int* __restrict__ blocksums,
                                                     int* __restrict__ blockbase, int nb) {
    int lane = threadIdx.x;
    int v = (lane < nb) ? blocksums[lane] : 0;
    int incl = v;
    #pragma unroll
    for (int off = 1; off < 64; off <<= 1) {
        int nbr = __shfl_up(incl, off, 64);
        if (lane >= off) incl += nbr;
    }
    if (lane < nb) blockbase[lane] = incl - v;
}

__global__ __launch_bounds__(256) void add_base(int* __restrict__ out,
                                                const int* __restrict__ blockbase, int n) {
    int i = blockIdx.x * 256 + threadIdx.x;
    if (i < n) out[i] += blockbase[i >> 11];
}

// ======================= sort: P3 coarse scatter (pairs) =======================
__global__ __launch_bounds__(256) void p3_scatter(const int* __restrict__ dst,
                                                  const int* __restrict__ src,
                                                  const int* __restrict__ tileScan,
                                                  int2* __restrict__ coarse) {
    __shared__ int cur[BUK];
    const int t = threadIdx.x, tile = blockIdx.x;
    for (int i = t; i < BUK; i += 256) cur[i] = tileScan[i * NT + tile];
    __syncthreads();
    const int base = tile * TS;
    for (int i = t; i < TS; i += 256) {
        int e = base + i;
        if (e < NE) {
            int d = dst[e];
            int p = atomicAdd(&cur[d >> 9], 1);
            coarse[p] = make_int2(d, src[e]);
        }
    }
}

// ======================= sort: P4 per-bucket exact CSR =======================
// One block per bucket (512 nodes). Computes offs for its nodes (replaces the
// old global hist+scan) and scatters src into its L2-resident ssrc region.
__global__ __launch_bounds__(256) void p4_build(const int2* __restrict__ coarse,
                                                const int* __restrict__ tileScan,
                                                int* __restrict__ offs,
                                                int* __restrict__ ssrc) {
    __shared__ int cnt[512];
    __shared__ int ts[256];
    const int b = blockIdx.x, t = threadIdx.x;
    const int n0 = b << 9;
    const int bs = tileScan[b * NT];
    const int be = (b == BUK - 1) ? NE : tileScan[(b + 1) * NT];
    cnt[t] = 0; cnt[t + 256] = 0;
    __syncthreads();
    for (int i = bs + t; i < be; i += 256)
        atomicAdd(&cnt[coarse[i].x - n0], 1);
    __syncthreads();
    int c0 = cnt[2 * t], c1 = cnt[2 * t + 1];
    ts[t] = c0 + c1;
    __syncthreads();
    for (int off = 1; off < 256; off <<= 1) {
        int add = (t >= off) ? ts[t - off] : 0;
        __syncthreads();
        ts[t] += add;
        __syncthreads();
    }
    int ex = (t == 0) ? 0 : ts[t - 1];         // exclusive over node pairs
    int o0 = bs + ex, o1 = o0 + c0;
    cnt[2 * t] = o0; cnt[2 * t + 1] = o1;       // cursors (own slots only)
    if (n0 + 2 * t < NN)     offs[n0 + 2 * t]     = o0;
    if (n0 + 2 * t + 1 < NN) offs[n0 + 2 * t + 1] = o1;
    if (b == BUK - 1 && t == 0) offs[NN] = NE;
    __syncthreads();
    for (int i = bs + t; i < be; i += 256) {
        int2 pr = coarse[i];
        int p = atomicAdd(&cnt[pr.x - n0], 1);
        ssrc[p] = pr.y;
    }
}

// ======================= bf16 path =======================
// xh layout: [NN][256] bf16; cols 0..127 = bf16(x), cols 128..255 = bf16(maxdiff)
__global__ __launch_bounds__(256) void prep_xh(const float* __restrict__ x,
                                               ushort_t* __restrict__ xh) {
    int i = blockIdx.x * 256 + threadIdx.x;
    if (i >= NN * C / 8) return;
    int node = i >> 4;
    int c0   = (i & 15) * 8;
    const float4* xp = (const float4*)(x + (long)i * 8);
    float4 v0 = xp[0], v1 = xp[1];
    ushort_t o[8] = { f2bf(v0.x), f2bf(v0.y), f2bf(v0.z), f2bf(v0.w),
                      f2bf(v1.x), f2bf(v1.y), f2bf(v1.z), f2bf(v1.w) };
    *(bf16x8*)(xh + (long)node * 256 + c0) = *(bf16x8*)o;
}

__global__ __launch_bounds__(256) void conv_w(const float* __restrict__ W,
                                              ushort_t* __restrict__ Wt) {
    int i = blockIdx.x * 256 + threadIdx.x;
    if (i >= 2 * C * C) return;
    int k = i >> 7, n = i & 127;
    Wt[n * 256 + k] = f2bf(W[i]);
}

__global__ __launch_bounds__(256) void node_min_bf16(
        const int* __restrict__ offs, const int* __restrict__ ssrc,
        ushort_t* __restrict__ xh) {
    int wid  = (blockIdx.x * 256 + threadIdx.x) >> 6;
    int lane = threadIdx.x & 63;
    if (wid >= NN) return;
    const int beg = offs[wid], end = offs[wid + 1];
    const uint_t* xp = (const uint_t*)xh;
    float m0 = INFINITY, m1 = INFINITY;
    int i = beg;
    for (; i + 4 <= end; i += 4) {
        uint_t a0 = xp[(long)ssrc[i]     * 128 + lane];
        uint_t a1 = xp[(long)ssrc[i + 1] * 128 + lane];
        uint_t a2 = xp[(long)ssrc[i + 2] * 128 + lane];
        uint_t a3 = xp[(long)ssrc[i + 3] * 128 + lane];
        m0 = fminf(m0, fminf(fminf(__uint_as_float(a0 << 16), __uint_as_float(a1 << 16)),
                             fminf(__uint_as_float(a2 << 16), __uint_as_float(a3 << 16))));
        m1 = fminf(m1, fminf(fminf(__uint_as_float(a0 & 0xffff0000u), __uint_as_float(a1 & 0xffff0000u)),
                             fminf(__uint_as_float(a2 & 0xffff0000u), __uint_as_float(a3 & 0xffff0000u))));
    }
    for (; i < end; ++i) {
        uint_t a = xp[(long)ssrc[i] * 128 + lane];
        m0 = fminf(m0, __uint_as_float(a << 16));
        m1 = fminf(m1, __uint_as_float(a & 0xffff0000u));
    }
    uint_t xd = xp[(long)wid * 128 + lane];
    float d0 = 0.0f, d1 = 0.0f;
    if (end > beg) {
        d0 = __uint_as_float(xd << 16)         - m0;
        d1 = __uint_as_float(xd & 0xffff0000u) - m1;
    }
    uint_t packed = (uint_t)f2bf(d0) | ((uint_t)f2bf(d1) << 16);
    ((uint_t*)xh)[(long)wid * 128 + 64 + lane] = packed;
}

// MFMA GEMM: out[N,128] = relu(h[N,256] @ W + b)
__global__ __launch_bounds__(256) void gemm_mfma(
        const ushort_t* __restrict__ xh, const ushort_t* __restrict__ Wt,
        const float* __restrict__ b, float* __restrict__ out) {
    const int w  = threadIdx.x >> 6;
    const int l  = threadIdx.x & 63;
    const int m0 = blockIdx.x * 64 + w * 16;
    int arow = m0 + (l & 15);
    if (arow >= NN) arow = NN - 1;
    const int kb = (l >> 4) * 8;

    f32x4 acc[8];
    #pragma unroll
    for (int n = 0; n < 8; ++n) acc[n] = (f32x4){0.f, 0.f, 0.f, 0.f};

    const ushort_t* ap    = xh + (long)arow * 256 + kb;
    const ushort_t* wbase = Wt + (l & 15) * 256 + kb;

    #pragma unroll
    for (int k0 = 0; k0 < 256; k0 += 32) {
        bf16x8 a = *(const bf16x8*)(ap + k0);
        #pragma unroll
        for (int n = 0; n < 8; ++n) {
            bf16x8 bb = *(const bf16x8*)(wbase + n * 16 * 256 + k0);
            acc[n] = __builtin_amdgcn_mfma_f32_16x16x32_bf16(a, bb, acc[n], 0, 0, 0);
        }
    }

    const int colb  = l & 15;
    const int rbase = m0 + ((l >> 4) << 2);
    #pragma unroll
    for (int n = 0; n < 8; ++n) {
        int col = n * 16 + colb;
        float bv = b[col];
        #pragma unroll
        for (int j = 0; j < 4; ++j) {
            int r = rbase + j;
            if (r < NN) out[(long)r * 128 + col] = fmaxf(acc[n][j] + bv, 0.0f);
        }
    }
}

// ======================= zero-ws fallback =======================
__global__ void init_neginf(float* __restrict__ p, int n) {
    int i = blockIdx.x * blockDim.x + threadIdx.x;
    if (i < n) p[i] = -INFINITY;
}

__device__ inline void amaxf(float* a, float v, float cur) {
    if (cur >= v) return;
    if (v >= 0.0f) atomicMax((int*)a, __float_as_int(v));
    else           atomicMin((unsigned int*)a, __float_as_uint(v));
}

__global__ __launch_bounds__(256) void edge_max(
        const float* __restrict__ x, const int* __restrict__ src,
        const int* __restrict__ dst, float* __restrict__ maxdiff) {
    long tid = (long)blockIdx.x * blockDim.x + threadIdx.x;
    int e = (int)(tid >> 5);
    if (e >= NE) return;
    int lane = (int)(tid & 31);
    int s = src[e], d = dst[e];
    int c0 = lane * 4;
    const float4 xd = *(const float4*)(x + (long)d * C + c0);
    const float4 xs = *(const float4*)(x + (long)s * C + c0);
    float4 df;
    df.x = xd.x - xs.x; df.y = xd.y - xs.y;
    df.z = xd.z - xs.z; df.w = xd.w - xs.w;
    float* o = maxdiff + (long)d * C + c0;
    float4 cur = *(const float4*)o;
    amaxf(o + 0, df.x, cur.x);
    amaxf(o + 1, df.y, cur.y);
    amaxf(o + 2, df.z, cur.z);
    amaxf(o + 3, df.w, cur.w);
}

#define TN 32
__global__ __launch_bounds__(256) void gemm_relu(
        const float* __restrict__ x, const float* __restrict__ W,
        const float* __restrict__ b, float* __restrict__ out) {
    __shared__ float h[TN][2 * C];
    const int nb = blockIdx.x * TN;
    const int t  = threadIdx.x;
    for (int i = t; i < TN * 2 * C / 4; i += 256) {
        int idx  = i * 4;
        int node = idx / (2 * C);
        int ci   = idx % (2 * C);
        float4 v;
        if (ci < C) {
            v = *(const float4*)(x + (long)(nb + node) * C + ci);
        } else {
            v = *(const float4*)(out + (long)(nb + node) * C + (ci - C));
            if (v.x == -INFINITY) v.x = 0.0f;
            if (v.y == -INFINITY) v.y = 0.0f;
            if (v.z == -INFINITY) v.z = 0.0f;
            if (v.w == -INFINITY) v.w = 0.0f;
        }
        *(float4*)&h[node][ci] = v;
    }
    __syncthreads();
    const int co = (t & 31) * 4;
    const int n0 = (t >> 5) * 4;
    float acc[4][4];
    #pragma unroll
    for (int i = 0; i < 4; ++i)
        #pragma unroll
        for (int j = 0; j < 4; ++j) acc[i][j] = 0.0f;
    for (int ci = 0; ci < 2 * C; ++ci) {
        float4 w = *(const float4*)(W + (long)ci * C + co);
        #pragma unroll
        for (int i = 0; i < 4; ++i) {
            float hv = h[n0 + i][ci];
            acc[i][0] = fmaf(hv, w.x, acc[i][0]);
            acc[i][1] = fmaf(hv, w.y, acc[i][1]);
            acc[i][2] = fmaf(hv, w.z, acc[i][2]);
            acc[i][3] = fmaf(hv, w.w, acc[i][3]);
        }
    }
    float4 bias = *(const float4*)(b + co);
    #pragma unroll
    for (int i = 0; i < 4; ++i) {
        float4 r;
        r.x = fmaxf(acc[i][0] + bias.x, 0.0f);
        r.y = fmaxf(acc[i][1] + bias.y, 0.0f);
        r.z = fmaxf(acc[i][2] + bias.z, 0.0f);
        r.w = fmaxf(acc[i][3] + bias.w, 0.0f);
        *(float4*)(out + (long)(nb + n0 + i) * C + co) = r;
    }
}

extern "C" void kernel_launch(void* const* d_in, const int* in_sizes, int n_in,
                              void* d_out, int out_size, void* d_ws, size_t ws_size,
                              hipStream_t stream) {
    const float* x   = (const float*)d_in[0];
    const float* W   = (const float*)d_in[1];
    const float* b   = (const float*)d_in[2];
    const int*   src = (const int*)d_in[3];
    const int*   dst = (const int*)d_in[4];
    float* out = (float*)d_out;

    // ws layout (ints unless noted):
    //   blocksums[64] | blockbase[64] | tileScan[NSC] | offs[NN+1] | ssrc[NE]
    //   | xh (NN*256 bf16, 64B-aligned)   [tileHistT + coarse alias into xh]
    //   | Wt (2C*C bf16)
    size_t ints_head = (size_t)128 + NSC + (NN + 1) + NE;
    size_t head_b    = ((ints_head * 4) + 255) & ~(size_t)255;
    size_t xh_b      = (size_t)NN * 256 * 2;          // 51.2 MB
    size_t wt_b      = (size_t)2 * C * C * 2;         // 64 KB
    size_t need      = head_b + xh_b + wt_b;

    if (ws_size >= need) {
        int* blocksums = (int*)d_ws;
        int* blockbase = blocksums + 64;
        int* tileScan  = blockbase + 64;
        int* offs      = tileScan + NSC;
        int* ssrc      = offs + NN + 1;
        ushort_t* xh   = (ushort_t*)((char*)d_ws + head_b);
        ushort_t* Wt   = (ushort_t*)((char*)d_ws + head_b + xh_b);
        // aliases inside xh region (dead before prep_xh runs):
        int*  tileHistT = (int*)xh;                   // NSC ints (P1->P2)
        int2* coarse    = (int2*)xh;                  // NE int2  (P3->P4)

        p1_hist<<<NT, 256, 0, stream>>>(dst, tileHistT);
        scan_partial<<<NBS, 256, 0, stream>>>(tileHistT, tileScan, blocksums, NSC);
        scan_blocksums<<<1, 64, 0, stream>>>(blocksums, blockbase, NBS);
        add_base<<<(NSC + 255) / 256, 256, 0, stream>>>(tileScan, blockbase, NSC);
        p3_scatter<<<NT, 256, 0, stream>>>(dst, src, tileScan, coarse);
        p4_build<<<BUK, 256, 0, stream>>>(coarse, tileScan, offs, ssrc);

        prep_xh<<<(NN * C / 8 + 255) / 256, 256, 0, stream>>>(x, xh);
        conv_w<<<(2 * C * C + 255) / 256, 256, 0, stream>>>(W, Wt);
        node_min_bf16<<<NN / 4, 256, 0, stream>>>(offs, ssrc, xh);
        gemm_mfma<<<(NN + 63) / 64, 256, 0, stream>>>(xh, Wt, b, out);
    } else {
        int n = NN * C;
        init_neginf<<<(n + 255) / 256, 256, 0, stream>>>(out, n);
        long threads = (long)NE * 32;
        edge_max<<<(int)((threads + 255) / 256), 256, 0, stream>>>(x, src, dst, out);
        gemm_relu<<<(NN + TN - 1) / TN, 256, 0, stream>>>(x, W, b, out);
    }
}

// Round 6
// 294.380 us; speedup vs baseline: 5.1738x; 1.0147x over previous
//
#include <hip/hip_runtime.h>
#include <math.h>

#define NN 100000
#define NE 1600000
#define C 128

#define TS 4096                       // edges per sort tile
#define NT ((NE + TS - 1) / TS)       // 391 tiles
#define BUK ((NN + 511) >> 9)         // 196 buckets of 512 nodes
#define NSC (BUK * NT)                // 76636 scan elements
#define NBS ((NSC + 2047) / 2048)     // 38 scan blocks (<=64)
#define PREP_BLKS (NN * C / 8 / 256)  // 6250
#define CONVW_BLKS (2 * C * C / 256)  // 128

typedef __attribute__((ext_vector_type(8))) short   bf16x8;
typedef __attribute__((ext_vector_type(4))) float   f32x4;
typedef unsigned short ushort_t;
typedef unsigned int   uint_t;

__device__ inline ushort_t f2bf(float f) {   // RTNE float -> bf16 bits
    union { float f; uint_t u; } a; a.f = f;
    uint_t r = a.u + 0x7fff + ((a.u >> 16) & 1);
    return (ushort_t)(r >> 16);
}

// =============== K1: merged setup (prep_xh | conv_w | p1_hist) ===============
// xh layout: [NN][256] bf16; cols 0..127 = bf16(x), cols 128..255 = maxdiff
__global__ __launch_bounds__(256) void k_setup(
        const float* __restrict__ x, ushort_t* __restrict__ xh,
        const float* __restrict__ W, ushort_t* __restrict__ Wt,
        const int* __restrict__ dst, int* __restrict__ tileHistT) {
    __shared__ int h[BUK];
    const int t  = threadIdx.x;
    const int bb = blockIdx.x;
    if (bb < PREP_BLKS) {                      // x -> bf16 rows of xh
        int i = bb * 256 + t;                  // one thread per 8 floats
        int node = i >> 4;
        int c0   = (i & 15) * 8;
        const float4* xp = (const float4*)(x + (long)i * 8);
        float4 v0 = xp[0], v1 = xp[1];
        ushort_t o[8] = { f2bf(v0.x), f2bf(v0.y), f2bf(v0.z), f2bf(v0.w),
                          f2bf(v1.x), f2bf(v1.y), f2bf(v1.z), f2bf(v1.w) };
        *(bf16x8*)(xh + (long)node * 256 + c0) = *(bf16x8*)o;
    } else if (bb < PREP_BLKS + CONVW_BLKS) {  // W [256][128] -> Wt bf16 [128][256]
        int i = (bb - PREP_BLKS) * 256 + t;
        int k = i >> 7, n = i & 127;
        Wt[n * 256 + k] = f2bf(W[i]);
    } else {                                   // tile histogram over 196 buckets
        const int tile = bb - PREP_BLKS - CONVW_BLKS;
        for (int i = t; i < BUK; i += 256) h[i] = 0;
        __syncthreads();
        const int base = tile * TS;
        for (int i = t; i < TS; i += 256) {
            int e = base + i;
            if (e < NE) atomicAdd(&h[dst[e] >> 9], 1);
        }
        __syncthreads();
        for (int i = t; i < BUK; i += 256) tileHistT[i * NT + tile] = h[i];
    }
}

// ======================= 2-kernel scan (base folded into consumers) ==========
__global__ __launch_bounds__(256) void scan_partial(const int* __restrict__ in,
                                                    int* __restrict__ out,
                                                    int* __restrict__ blocksums,
                                                    int n) {
    __shared__ int ts[256];
    const int t = threadIdx.x;
    const int base = blockIdx.x * 2048 + t * 8;
    int c[8];
    int s = 0;
    #pragma unroll
    for (int j = 0; j < 8; ++j) {
        int i = base + j;
        c[j] = (i < n) ? in[i] : 0;
        s += c[j];
    }
    ts[t] = s;
    __syncthreads();
    for (int off = 1; off < 256; off <<= 1) {
        int add = (t >= off) ? ts[t - off] : 0;
        __syncthreads();
        ts[t] += add;
        __syncthreads();
    }
    int run = (t == 0) ? 0 : ts[t - 1];
    #pragma unroll
    for (int j = 0; j < 8; ++j) {
        int i = base + j;
        if (i < n) out[i] = run;
        run += c[j];
    }
    if (t == 255) blocksums[blockIdx.x] = ts[255];
}

__global__ __launch_bounds__(64) void scan_blocksums(const int* __restrict__ blocksums,
                                                     int* __restrict__ blockbase, int nb) {
    int lane = threadIdx.x;
    int v = (lane < nb) ? blocksums[lane] : 0;
    int incl = v;
    #pragma unroll
    for (int off = 1; off < 64; off <<= 1) {
        int nbr = __shfl_up(incl, off, 64);
        if (lane >= off) incl += nbr;
    }
    if (lane < nb) blockbase[lane] = incl - v;
}

// ======================= P3: coarse scatter of packed (local9|src17) =========
__global__ __launch_bounds__(256) void p3_scatter(const int* __restrict__ dst,
                                                  const int* __restrict__ src,
                                                  const int* __restrict__ tileScan,
                                                  const int* __restrict__ blockbase,
                                                  uint_t* __restrict__ coarse) {
    __shared__ int cur[BUK];
    const int t = threadIdx.x, tile = blockIdx.x;
    for (int i = t; i < BUK; i += 256) {
        int idx = i * NT + tile;
        cur[i] = tileScan[idx] + blockbase[idx >> 11];
    }
    __syncthreads();
    const int base = tile * TS;
    for (int i = t; i < TS; i += 256) {
        int e = base + i;
        if (e < NE) {
            int d = dst[e];
            int p = atomicAdd(&cur[d >> 9], 1);
            coarse[p] = ((uint_t)(d & 511) << 17) | (uint_t)src[e];
        }
    }
}

// ======================= P4: per-bucket exact CSR ============================
__global__ __launch_bounds__(256) void p4_build(const uint_t* __restrict__ coarse,
                                                const int* __restrict__ tileScan,
                                                const int* __restrict__ blockbase,
                                                int* __restrict__ offs,
                                                int* __restrict__ ssrc) {
    __shared__ int cnt[512];
    __shared__ int ts[256];
    const int b = blockIdx.x, t = threadIdx.x;
    const int n0 = b << 9;
    const int i0 = b * NT;
    const int bs = tileScan[i0] + blockbase[i0 >> 11];
    int be;
    if (b == BUK - 1) be = NE;
    else { int i1 = (b + 1) * NT; be = tileScan[i1] + blockbase[i1 >> 11]; }
    cnt[t] = 0; cnt[t + 256] = 0;
    __syncthreads();
    for (int i = bs + t; i < be; i += 256)
        atomicAdd(&cnt[(int)(coarse[i] >> 17)], 1);
    __syncthreads();
    int c0 = cnt[2 * t], c1 = cnt[2 * t + 1];
    ts[t] = c0 + c1;
    __syncthreads();
    for (int off = 1; off < 256; off <<= 1) {
        int add = (t >= off) ? ts[t - off] : 0;
        __syncthreads();
        ts[t] += add;
        __syncthreads();
    }
    int ex = (t == 0) ? 0 : ts[t - 1];
    int o0 = bs + ex, o1 = o0 + c0;
    cnt[2 * t] = o0; cnt[2 * t + 1] = o1;
    if (n0 + 2 * t < NN)     offs[n0 + 2 * t]     = o0;
    if (n0 + 2 * t + 1 < NN) offs[n0 + 2 * t + 1] = o1;
    if (b == BUK - 1 && t == 0) offs[NN] = NE;
    __syncthreads();
    for (int i = bs + t; i < be; i += 256) {
        uint_t pk = coarse[i];
        int p = atomicAdd(&cnt[(int)(pk >> 17)], 1);
        ssrc[p] = (int)(pk & 0x1FFFF);
    }
}

// ======================= node min v2: 4 edges/wave, dwordx4 gathers ==========
#define ACCQ(u)  { m[0] = fminf(m[0], __uint_as_float((u).x << 16));          \
                   m[1] = fminf(m[1], __uint_as_float((u).x & 0xffff0000u));  \
                   m[2] = fminf(m[2], __uint_as_float((u).y << 16));          \
                   m[3] = fminf(m[3], __uint_as_float((u).y & 0xffff0000u));  \
                   m[4] = fminf(m[4], __uint_as_float((u).z << 16));          \
                   m[5] = fminf(m[5], __uint_as_float((u).z & 0xffff0000u));  \
                   m[6] = fminf(m[6], __uint_as_float((u).w << 16));          \
                   m[7] = fminf(m[7], __uint_as_float((u).w & 0xffff0000u)); }

__global__ __launch_bounds__(256) void node_min_v2(
        const int* __restrict__ offs, const int* __restrict__ ssrc,
        ushort_t* __restrict__ xh) {
    const int wid  = (blockIdx.x * 256 + threadIdx.x) >> 6;
    const int lane = threadIdx.x & 63;
    if (wid >= NN) return;
    const int g = lane >> 4;          // edge slot 0..3
    const int s = lane & 15;          // 16B chunk -> channels [8s..8s+8)
    const int beg = offs[wid], end = offs[wid + 1];
    const char* xb = (const char*)xh;
    float m[8];
    #pragma unroll
    for (int j = 0; j < 8; ++j) m[j] = INFINITY;
    int i = beg;
    for (; i + 8 <= end; i += 8) {                 // 8 edges per iter (unroll 2)
        int e0 = ssrc[i + g];
        int e1 = ssrc[i + 4 + g];
        uint4 a = *(const uint4*)(xb + (long)e0 * 512 + s * 16);
        uint4 bq = *(const uint4*)(xb + (long)e1 * 512 + s * 16);
        ACCQ(a);
        ACCQ(bq);
    }
    for (; i < end; i += 4) {                      // masked tail
        int e = i + g;
        int idx = ssrc[(e < end) ? e : (end - 1)];
        uint4 a = *(const uint4*)(xb + (long)idx * 512 + s * 16);
        if (e < end) ACCQ(a);
    }
    #pragma unroll
    for (int j = 0; j < 8; ++j) {                  // combine 4 edge slots
        m[j] = fminf(m[j], __shfl_xor(m[j], 16, 64));
        m[j] = fminf(m[j], __shfl_xor(m[j], 32, 64));
    }
    if (g == 0) {                                  // 16 lanes write the row
        uint4 xd = *(const uint4*)(xb + (long)wid * 512 + s * 16);
        uint_t xu[4] = { xd.x, xd.y, xd.z, xd.w };
        bool has = end > beg;
        uint4 o;
        uint_t* op = (uint_t*)&o;
        #pragma unroll
        for (int j = 0; j < 4; ++j) {
            float lo = has ? (__uint_as_float(xu[j] << 16)         - m[2 * j])     : 0.0f;
            float hi = has ? (__uint_as_float(xu[j] & 0xffff0000u) - m[2 * j + 1]) : 0.0f;
            op[j] = (uint_t)f2bf(lo) | ((uint_t)f2bf(hi) << 16);
        }
        *(uint4*)((char*)xh + (long)wid * 512 + 256 + s * 16) = o;
    }
}

// ======================= MFMA GEMM: relu(h @ W + b) ==========================
__global__ __launch_bounds__(256) void gemm_mfma(
        const ushort_t* __restrict__ xh, const ushort_t* __restrict__ Wt,
        const float* __restrict__ b, float* __restrict__ out) {
    const int w  = threadIdx.x >> 6;
    const int l  = threadIdx.x & 63;
    const int m0 = blockIdx.x * 64 + w * 16;
    int arow = m0 + (l & 15);
    if (arow >= NN) arow = NN - 1;
    const int kb = (l >> 4) * 8;

    f32x4 acc[8];
    #pragma unroll
    for (int n = 0; n < 8; ++n) acc[n] = (f32x4){0.f, 0.f, 0.f, 0.f};

    const ushort_t* ap    = xh + (long)arow * 256 + kb;
    const ushort_t* wbase = Wt + (l & 15) * 256 + kb;

    #pragma unroll
    for (int k0 = 0; k0 < 256; k0 += 32) {
        bf16x8 a = *(const bf16x8*)(ap + k0);
        #pragma unroll
        for (int n = 0; n < 8; ++n) {
            bf16x8 bb = *(const bf16x8*)(wbase + n * 16 * 256 + k0);
            acc[n] = __builtin_amdgcn_mfma_f32_16x16x32_bf16(a, bb, acc[n], 0, 0, 0);
        }
    }

    const int colb  = l & 15;
    const int rbase = m0 + ((l >> 4) << 2);
    #pragma unroll
    for (int n = 0; n < 8; ++n) {
        int col = n * 16 + colb;
        float bv = b[col];
        #pragma unroll
        for (int j = 0; j < 4; ++j) {
            int r = rbase + j;
            if (r < NN) out[(long)r * 128 + col] = fmaxf(acc[n][j] + bv, 0.0f);
        }
    }
}

// ======================= zero-ws fallback ====================================
__global__ void init_neginf(float* __restrict__ p, int n) {
    int i = blockIdx.x * blockDim.x + threadIdx.x;
    if (i < n) p[i] = -INFINITY;
}

__device__ inline void amaxf(float* a, float v, float cur) {
    if (cur >= v) return;
    if (v >= 0.0f) atomicMax((int*)a, __float_as_int(v));
    else           atomicMin((unsigned int*)a, __float_as_uint(v));
}

__global__ __launch_bounds__(256) void edge_max(
        const float* __restrict__ x, const int* __restrict__ src,
        const int* __restrict__ dst, float* __restrict__ maxdiff) {
    long tid = (long)blockIdx.x * blockDim.x + threadIdx.x;
    int e = (int)(tid >> 5);
    if (e >= NE) return;
    int lane = (int)(tid & 31);
    int s = src[e], d = dst[e];
    int c0 = lane * 4;
    const float4 xd = *(const float4*)(x + (long)d * C + c0);
    const float4 xs = *(const float4*)(x + (long)s * C + c0);
    float4 df;
    df.x = xd.x - xs.x; df.y = xd.y - xs.y;
    df.z = xd.z - xs.z; df.w = xd.w - xs.w;
    float* o = maxdiff + (long)d * C + c0;
    float4 cur = *(const float4*)o;
    amaxf(o + 0, df.x, cur.x);
    amaxf(o + 1, df.y, cur.y);
    amaxf(o + 2, df.z, cur.z);
    amaxf(o + 3, df.w, cur.w);
}

#define TN 32
__global__ __launch_bounds__(256) void gemm_relu(
        const float* __restrict__ x, const float* __restrict__ W,
        const float* __restrict__ b, float* __restrict__ out) {
    __shared__ float h[TN][2 * C];
    const int nb = blockIdx.x * TN;
    const int t  = threadIdx.x;
    for (int i = t; i < TN * 2 * C / 4; i += 256) {
        int idx  = i * 4;
        int node = idx / (2 * C);
        int ci   = idx % (2 * C);
        float4 v;
        if (ci < C) {
            v = *(const float4*)(x + (long)(nb + node) * C + ci);
        } else {
            v = *(const float4*)(out + (long)(nb + node) * C + (ci - C));
            if (v.x == -INFINITY) v.x = 0.0f;
            if (v.y == -INFINITY) v.y = 0.0f;
            if (v.z == -INFINITY) v.z = 0.0f;
            if (v.w == -INFINITY) v.w = 0.0f;
        }
        *(float4*)&h[node][ci] = v;
    }
    __syncthreads();
    const int co = (t & 31) * 4;
    const int n0 = (t >> 5) * 4;
    float acc[4][4];
    #pragma unroll
    for (int i = 0; i < 4; ++i)
        #pragma unroll
        for (int j = 0; j < 4; ++j) acc[i][j] = 0.0f;
    for (int ci = 0; ci < 2 * C; ++ci) {
        float4 w = *(const float4*)(W + (long)ci * C + co);
        #pragma unroll
        for (int i = 0; i < 4; ++i) {
            float hv = h[n0 + i][ci];
            acc[i][0] = fmaf(hv, w.x, acc[i][0]);
            acc[i][1] = fmaf(hv, w.y, acc[i][1]);
            acc[i][2] = fmaf(hv, w.z, acc[i][2]);
            acc[i][3] = fmaf(hv, w.w, acc[i][3]);
        }
    }
    float4 bias = *(const float4*)(b + co);
    #pragma unroll
    for (int i = 0; i < 4; ++i) {
        float4 r;
        r.x = fmaxf(acc[i][0] + bias.x, 0.0f);
        r.y = fmaxf(acc[i][1] + bias.y, 0.0f);
        r.z = fmaxf(acc[i][2] + bias.z, 0.0f);
        r.w = fmaxf(acc[i][3] + bias.w, 0.0f);
        *(float4*)(out + (long)(nb + n0 + i) * C + co) = r;
    }
}

extern "C" void kernel_launch(void* const* d_in, const int* in_sizes, int n_in,
                              void* d_out, int out_size, void* d_ws, size_t ws_size,
                              hipStream_t stream) {
    const float* x   = (const float*)d_in[0];
    const float* W   = (const float*)d_in[1];
    const float* b   = (const float*)d_in[2];
    const int*   src = (const int*)d_in[3];
    const int*   dst = (const int*)d_in[4];
    float* out = (float*)d_out;

    // ws: blocksums[64]|blockbase[64]|tileScan[NSC]|offs[NN+1]|ssrc[NE] | xh | Wt
    // tileHistT aliases ssrc (dead before p4 writes ssrc).
    // coarse (NE uints) lives in d_out (dead until gemm writes it).
    size_t ints_head = (size_t)128 + NSC + (NN + 1) + NE;
    size_t head_b    = ((ints_head * 4) + 255) & ~(size_t)255;
    size_t xh_b      = (size_t)NN * 256 * 2;          // 51.2 MB
    size_t wt_b      = (size_t)2 * C * C * 2;         // 64 KB
    size_t need      = head_b + xh_b + wt_b;

    if (ws_size >= need) {
        int* blocksums = (int*)d_ws;
        int* blockbase = blocksums + 64;
        int* tileScan  = blockbase + 64;
        int* offs      = tileScan + NSC;
        int* ssrc      = offs + NN + 1;
        ushort_t* xh   = (ushort_t*)((char*)d_ws + head_b);
        ushort_t* Wt   = (ushort_t*)((char*)d_ws + head_b + xh_b);
        int*    tileHistT = ssrc;                     // alias (NSC <= NE)
        uint_t* coarse    = (uint_t*)d_out;           // alias (NE <= out elems)

        k_setup<<<PREP_BLKS + CONVW_BLKS + NT, 256, 0, stream>>>(x, xh, W, Wt, dst, tileHistT);
        scan_partial<<<NBS, 256, 0, stream>>>(tileHistT, tileScan, blocksums, NSC);
        scan_blocksums<<<1, 64, 0, stream>>>(blocksums, blockbase, NBS);
        p3_scatter<<<NT, 256, 0, stream>>>(dst, src, tileScan, blockbase, coarse);
        p4_build<<<BUK, 256, 0, stream>>>(coarse, tileScan, blockbase, offs, ssrc);
        node_min_v2<<<NN / 4, 256, 0, stream>>>(offs, ssrc, xh);
        gemm_mfma<<<(NN + 63) / 64, 256, 0, stream>>>(xh, Wt, b, out);
    } else {
        int n = NN * C;
        init_neginf<<<(n + 255) / 256, 256, 0, stream>>>(out, n);
        long threads = (long)NE * 32;
        edge_max<<<(int)((threads + 255) / 256), 256, 0, stream>>>(x, src, dst, out);
        gemm_relu<<<(NN + TN - 1) / TN, 256, 0, stream>>>(x, W, b, out);
    }
}

// Round 7
// 269.421 us; speedup vs baseline: 5.6531x; 1.0926x over previous
//
#include <hip/hip_runtime.h>
#include <math.h>

#define NN 100000
#define NE 1600000
#define C 128

#define TS 4096                       // edges per sort tile
#define NT ((NE + TS - 1) / TS)       // 391 tiles
#define BUK ((NN + 511) >> 9)         // 196 buckets of 512 nodes
#define NSC (BUK * NT)                // 76636 scan elements
#define NBS ((NSC + 2047) / 2048)     // 38 scan blocks (<=64)
#define PREP_BLKS (NN * C / 8 / 256)  // 6250
#define CONVW_BLKS (2 * C * C / 256)  // 128
#define GM 64                         // gemm rows per block

typedef __attribute__((ext_vector_type(8))) short   bf16x8;
typedef __attribute__((ext_vector_type(4))) float   f32x4;
typedef unsigned short ushort_t;
typedef unsigned int   uint_t;

__device__ inline ushort_t f2bf(float f) {   // RTNE float -> bf16 bits
    union { float f; uint_t u; } a; a.f = f;
    uint_t r = a.u + 0x7fff + ((a.u >> 16) & 1);
    return (ushort_t)(r >> 16);
}

// =============== K1: merged setup (prep_xh | conv_w | p1_hist) ===============
// xh layout: [NN][256] bf16; cols 0..127 = bf16(x), cols 128..255 = maxdiff
__global__ __launch_bounds__(256) void k_setup(
        const float* __restrict__ x, ushort_t* __restrict__ xh,
        const float* __restrict__ W, ushort_t* __restrict__ Wt,
        const int* __restrict__ dst, int* __restrict__ tileHistT) {
    __shared__ int h[BUK];
    const int t  = threadIdx.x;
    const int bb = blockIdx.x;
    if (bb < PREP_BLKS) {                      // x -> bf16 rows of xh
        int i = bb * 256 + t;                  // one thread per 8 floats
        int node = i >> 4;
        int c0   = (i & 15) * 8;
        const float4* xp = (const float4*)(x + (long)i * 8);
        float4 v0 = xp[0], v1 = xp[1];
        ushort_t o[8] = { f2bf(v0.x), f2bf(v0.y), f2bf(v0.z), f2bf(v0.w),
                          f2bf(v1.x), f2bf(v1.y), f2bf(v1.z), f2bf(v1.w) };
        *(bf16x8*)(xh + (long)node * 256 + c0) = *(bf16x8*)o;
    } else if (bb < PREP_BLKS + CONVW_BLKS) {  // W [256][128] -> Wt bf16 [128][256]
        int i = (bb - PREP_BLKS) * 256 + t;
        int k = i >> 7, n = i & 127;
        Wt[n * 256 + k] = f2bf(W[i]);
    } else {                                   // tile histogram over 196 buckets
        const int tile = bb - PREP_BLKS - CONVW_BLKS;
        for (int i = t; i < BUK; i += 256) h[i] = 0;
        __syncthreads();
        const int base = tile * TS;
        for (int i = t; i < TS; i += 256) {
            int e = base + i;
            if (e < NE) atomicAdd(&h[dst[e] >> 9], 1);
        }
        __syncthreads();
        for (int i = t; i < BUK; i += 256) tileHistT[i * NT + tile] = h[i];
    }
}

// ======================= 2-kernel scan (base folded into consumers) ==========
__global__ __launch_bounds__(256) void scan_partial(const int* __restrict__ in,
                                                    int* __restrict__ out,
                                                    int* __restrict__ blocksums,
                                                    int n) {
    __shared__ int ts[256];
    const int t = threadIdx.x;
    const int base = blockIdx.x * 2048 + t * 8;
    int c[8];
    int s = 0;
    #pragma unroll
    for (int j = 0; j < 8; ++j) {
        int i = base + j;
        c[j] = (i < n) ? in[i] : 0;
        s += c[j];
    }
    ts[t] = s;
    __syncthreads();
    for (int off = 1; off < 256; off <<= 1) {
        int add = (t >= off) ? ts[t - off] : 0;
        __syncthreads();
        ts[t] += add;
        __syncthreads();
    }
    int run = (t == 0) ? 0 : ts[t - 1];
    #pragma unroll
    for (int j = 0; j < 8; ++j) {
        int i = base + j;
        if (i < n) out[i] = run;
        run += c[j];
    }
    if (t == 255) blocksums[blockIdx.x] = ts[255];
}

__global__ __launch_bounds__(64) void scan_blocksums(const int* __restrict__ blocksums,
                                                     int* __restrict__ blockbase, int nb) {
    int lane = threadIdx.x;
    int v = (lane < nb) ? blocksums[lane] : 0;
    int incl = v;
    #pragma unroll
    for (int off = 1; off < 64; off <<= 1) {
        int nbr = __shfl_up(incl, off, 64);
        if (lane >= off) incl += nbr;
    }
    if (lane < nb) blockbase[lane] = incl - v;
}

// ======================= P3: coarse scatter of packed (local9|src17) =========
__global__ __launch_bounds__(256) void p3_scatter(const int* __restrict__ dst,
                                                  const int* __restrict__ src,
                                                  const int* __restrict__ tileScan,
                                                  const int* __restrict__ blockbase,
                                                  uint_t* __restrict__ coarse) {
    __shared__ int cur[BUK];
    const int t = threadIdx.x, tile = blockIdx.x;
    for (int i = t; i < BUK; i += 256) {
        int idx = i * NT + tile;
        cur[i] = tileScan[idx] + blockbase[idx >> 11];
    }
    __syncthreads();
    const int base = tile * TS;
    for (int i = t; i < TS; i += 256) {
        int e = base + i;
        if (e < NE) {
            int d = dst[e];
            int p = atomicAdd(&cur[d >> 9], 1);
            coarse[p] = ((uint_t)(d & 511) << 17) | (uint_t)src[e];
        }
    }
}

// ======================= P4: per-bucket exact CSR ============================
__global__ __launch_bounds__(256) void p4_build(const uint_t* __restrict__ coarse,
                                                const int* __restrict__ tileScan,
                                                const int* __restrict__ blockbase,
                                                int* __restrict__ offs,
                                                int* __restrict__ ssrc) {
    __shared__ int cnt[512];
    __shared__ int ts[256];
    const int b = blockIdx.x, t = threadIdx.x;
    const int n0 = b << 9;
    const int i0 = b * NT;
    const int bs = tileScan[i0] + blockbase[i0 >> 11];
    int be;
    if (b == BUK - 1) be = NE;
    else { int i1 = (b + 1) * NT; be = tileScan[i1] + blockbase[i1 >> 11]; }
    cnt[t] = 0; cnt[t + 256] = 0;
    __syncthreads();
    for (int i = bs + t; i < be; i += 256)
        atomicAdd(&cnt[(int)(coarse[i] >> 17)], 1);
    __syncthreads();
    int c0 = cnt[2 * t], c1 = cnt[2 * t + 1];
    ts[t] = c0 + c1;
    __syncthreads();
    for (int off = 1; off < 256; off <<= 1) {
        int add = (t >= off) ? ts[t - off] : 0;
        __syncthreads();
        ts[t] += add;
        __syncthreads();
    }
    int ex = (t == 0) ? 0 : ts[t - 1];
    int o0 = bs + ex, o1 = o0 + c0;
    cnt[2 * t] = o0; cnt[2 * t + 1] = o1;
    if (n0 + 2 * t < NN)     offs[n0 + 2 * t]     = o0;
    if (n0 + 2 * t + 1 < NN) offs[n0 + 2 * t + 1] = o1;
    if (b == BUK - 1 && t == 0) offs[NN] = NE;
    __syncthreads();
    for (int i = bs + t; i < be; i += 256) {
        uint_t pk = coarse[i];
        int p = atomicAdd(&cnt[(int)(pk >> 17)], 1);
        ssrc[p] = (int)(pk & 0x1FFFF);
    }
}

// ======================= node min v2: 4 edges/wave, dwordx4 gathers ==========
#define ACCQ(u)  { m[0] = fminf(m[0], __uint_as_float((u).x << 16));          \
                   m[1] = fminf(m[1], __uint_as_float((u).x & 0xffff0000u));  \
                   m[2] = fminf(m[2], __uint_as_float((u).y << 16));          \
                   m[3] = fminf(m[3], __uint_as_float((u).y & 0xffff0000u));  \
                   m[4] = fminf(m[4], __uint_as_float((u).z << 16));          \
                   m[5] = fminf(m[5], __uint_as_float((u).z & 0xffff0000u));  \
                   m[6] = fminf(m[6], __uint_as_float((u).w << 16));          \
                   m[7] = fminf(m[7], __uint_as_float((u).w & 0xffff0000u)); }

__global__ __launch_bounds__(256) void node_min_v2(
        const int* __restrict__ offs, const int* __restrict__ ssrc,
        ushort_t* __restrict__ xh) {
    const int wid  = (blockIdx.x * 256 + threadIdx.x) >> 6;
    const int lane = threadIdx.x & 63;
    if (wid >= NN) return;
    const int g = lane >> 4;          // edge slot 0..3
    const int s = lane & 15;          // 16B chunk -> channels [8s..8s+8)
    const int beg = offs[wid], end = offs[wid + 1];
    const char* xb = (const char*)xh;
    float m[8];
    #pragma unroll
    for (int j = 0; j < 8; ++j) m[j] = INFINITY;
    int i = beg;
    for (; i + 8 <= end; i += 8) {                 // 8 edges per iter (unroll 2)
        int e0 = ssrc[i + g];
        int e1 = ssrc[i + 4 + g];
        uint4 a = *(const uint4*)(xb + (long)e0 * 512 + s * 16);
        uint4 bq = *(const uint4*)(xb + (long)e1 * 512 + s * 16);
        ACCQ(a);
        ACCQ(bq);
    }
    for (; i < end; i += 4) {                      // masked tail
        int e = i + g;
        int idx = ssrc[(e < end) ? e : (end - 1)];
        uint4 a = *(const uint4*)(xb + (long)idx * 512 + s * 16);
        if (e < end) ACCQ(a);
    }
    #pragma unroll
    for (int j = 0; j < 8; ++j) {                  // combine 4 edge slots
        m[j] = fminf(m[j], __shfl_xor(m[j], 16, 64));
        m[j] = fminf(m[j], __shfl_xor(m[j], 32, 64));
    }
    if (g == 0) {                                  // 16 lanes write the row
        uint4 xd = *(const uint4*)(xb + (long)wid * 512 + s * 16);
        uint_t xu[4] = { xd.x, xd.y, xd.z, xd.w };
        bool has = end > beg;
        uint4 o;
        uint_t* op = (uint_t*)&o;
        #pragma unroll
        for (int j = 0; j < 4; ++j) {
            float lo = has ? (__uint_as_float(xu[j] << 16)         - m[2 * j])     : 0.0f;
            float hi = has ? (__uint_as_float(xu[j] & 0xffff0000u) - m[2 * j + 1]) : 0.0f;
            op[j] = (uint_t)f2bf(lo) | ((uint_t)f2bf(hi) << 16);
        }
        *(uint4*)((char*)xh + (long)wid * 512 + 256 + s * 16) = o;
    }
}

// ======= MFMA GEMM v2: B fully in registers, per-wave 32-col slice ===========
// Block = 4 waves; wave w owns cols [w*32, w*32+32). Each block does GM rows.
__global__ __launch_bounds__(256) void gemm_mfma(
        const ushort_t* __restrict__ xh, const ushort_t* __restrict__ Wt,
        const float* __restrict__ b, float* __restrict__ out) {
    const int w    = threadIdx.x >> 6;
    const int l    = threadIdx.x & 63;
    const int wcol = w * 32;
    const int lr   = l & 15;              // row-in-tile / col-in-tile
    const int kb   = (l >> 4) * 8;        // k-chunk base

    // B in registers: bb[n][k0]  (64 VGPR) + bias per lane-col
    bf16x8 bb[2][8];
    float  bv[2];
    #pragma unroll
    for (int n = 0; n < 2; ++n) {
        int col = wcol + n * 16 + lr;
        bv[n] = b[col];
        const ushort_t* wp = Wt + (long)col * 256 + kb;
        #pragma unroll
        for (int k0 = 0; k0 < 8; ++k0)
            bb[n][k0] = *(const bf16x8*)(wp + k0 * 32);
    }

    const int mb0 = blockIdx.x * GM;
    #pragma unroll
    for (int mt = 0; mt < GM / 16; ++mt) {
        int mbase = mb0 + mt * 16;
        int arow = mbase + lr;
        if (arow >= NN) arow = NN - 1;    // clamp; stores guarded
        const ushort_t* ap = xh + (long)arow * 256 + kb;
        bf16x8 a[8];
        #pragma unroll
        for (int k0 = 0; k0 < 8; ++k0) a[k0] = *(const bf16x8*)(ap + k0 * 32);

        f32x4 acc0 = (f32x4){0.f, 0.f, 0.f, 0.f};
        f32x4 acc1 = (f32x4){0.f, 0.f, 0.f, 0.f};
        #pragma unroll
        for (int k0 = 0; k0 < 8; ++k0) {
            acc0 = __builtin_amdgcn_mfma_f32_16x16x32_bf16(a[k0], bb[0][k0], acc0, 0, 0, 0);
            acc1 = __builtin_amdgcn_mfma_f32_16x16x32_bf16(a[k0], bb[1][k0], acc1, 0, 0, 0);
        }

        int rbase = mbase + ((l >> 4) << 2);
        int col0 = wcol + lr;
        #pragma unroll
        for (int j = 0; j < 4; ++j) {
            int r = rbase + j;
            if (r < NN) {
                out[(long)r * 128 + col0]      = fmaxf(acc0[j] + bv[0], 0.0f);
                out[(long)r * 128 + col0 + 16] = fmaxf(acc1[j] + bv[1], 0.0f);
            }
        }
    }
}

// ======================= zero-ws fallback ====================================
__global__ void init_neginf(float* __restrict__ p, int n) {
    int i = blockIdx.x * blockDim.x + threadIdx.x;
    if (i < n) p[i] = -INFINITY;
}

__device__ inline void amaxf(float* a, float v, float cur) {
    if (cur >= v) return;
    if (v >= 0.0f) atomicMax((int*)a, __float_as_int(v));
    else           atomicMin((unsigned int*)a, __float_as_uint(v));
}

__global__ __launch_bounds__(256) void edge_max(
        const float* __restrict__ x, const int* __restrict__ src,
        const int* __restrict__ dst, float* __restrict__ maxdiff) {
    long tid = (long)blockIdx.x * blockDim.x + threadIdx.x;
    int e = (int)(tid >> 5);
    if (e >= NE) return;
    int lane = (int)(tid & 31);
    int s = src[e], d = dst[e];
    int c0 = lane * 4;
    const float4 xd = *(const float4*)(x + (long)d * C + c0);
    const float4 xs = *(const float4*)(x + (long)s * C + c0);
    float4 df;
    df.x = xd.x - xs.x; df.y = xd.y - xs.y;
    df.z = xd.z - xs.z; df.w = xd.w - xs.w;
    float* o = maxdiff + (long)d * C + c0;
    float4 cur = *(const float4*)o;
    amaxf(o + 0, df.x, cur.x);
    amaxf(o + 1, df.y, cur.y);
    amaxf(o + 2, df.z, cur.z);
    amaxf(o + 3, df.w, cur.w);
}

#define TN 32
__global__ __launch_bounds__(256) void gemm_relu(
        const float* __restrict__ x, const float* __restrict__ W,
        const float* __restrict__ b, float* __restrict__ out) {
    __shared__ float h[TN][2 * C];
    const int nb = blockIdx.x * TN;
    const int t  = threadIdx.x;
    for (int i = t; i < TN * 2 * C / 4; i += 256) {
        int idx  = i * 4;
        int node = idx / (2 * C);
        int ci   = idx % (2 * C);
        float4 v;
        if (ci < C) {
            v = *(const float4*)(x + (long)(nb + node) * C + ci);
        } else {
            v = *(const float4*)(out + (long)(nb + node) * C + (ci - C));
            if (v.x == -INFINITY) v.x = 0.0f;
            if (v.y == -INFINITY) v.y = 0.0f;
            if (v.z == -INFINITY) v.z = 0.0f;
            if (v.w == -INFINITY) v.w = 0.0f;
        }
        *(float4*)&h[node][ci] = v;
    }
    __syncthreads();
    const int co = (t & 31) * 4;
    const int n0 = (t >> 5) * 4;
    float acc[4][4];
    #pragma unroll
    for (int i = 0; i < 4; ++i)
        #pragma unroll
        for (int j = 0; j < 4; ++j) acc[i][j] = 0.0f;
    for (int ci = 0; ci < 2 * C; ++ci) {
        float4 w = *(const float4*)(W + (long)ci * C + co);
        #pragma unroll
        for (int i = 0; i < 4; ++i) {
            float hv = h[n0 + i][ci];
            acc[i][0] = fmaf(hv, w.x, acc[i][0]);
            acc[i][1] = fmaf(hv, w.y, acc[i][1]);
            acc[i][2] = fmaf(hv, w.z, acc[i][2]);
            acc[i][3] = fmaf(hv, w.w, acc[i][3]);
        }
    }
    float4 bias = *(const float4*)(b + co);
    #pragma unroll
    for (int i = 0; i < 4; ++i) {
        float4 r;
        r.x = fmaxf(acc[i][0] + bias.x, 0.0f);
        r.y = fmaxf(acc[i][1] + bias.y, 0.0f);
        r.z = fmaxf(acc[i][2] + bias.z, 0.0f);
        r.w = fmaxf(acc[i][3] + bias.w, 0.0f);
        *(float4*)(out + (long)(nb + n0 + i) * C + co) = r;
    }
}

extern "C" void kernel_launch(void* const* d_in, const int* in_sizes, int n_in,
                              void* d_out, int out_size, void* d_ws, size_t ws_size,
                              hipStream_t stream) {
    const float* x   = (const float*)d_in[0];
    const float* W   = (const float*)d_in[1];
    const float* b   = (const float*)d_in[2];
    const int*   src = (const int*)d_in[3];
    const int*   dst = (const int*)d_in[4];
    float* out = (float*)d_out;

    // ws: blocksums[64]|blockbase[64]|tileScan[NSC]|offs[NN+1]|ssrc[NE] | xh | Wt
    // tileHistT aliases ssrc (dead before p4 writes ssrc).
    // coarse (NE uints) lives in d_out (dead until gemm writes it).
    size_t ints_head = (size_t)128 + NSC + (NN + 1) + NE;
    size_t head_b    = ((ints_head * 4) + 255) & ~(size_t)255;
    size_t xh_b      = (size_t)NN * 256 * 2;          // 51.2 MB
    size_t wt_b      = (size_t)2 * C * C * 2;         // 64 KB
    size_t need      = head_b + xh_b + wt_b;

    if (ws_size >= need) {
        int* blocksums = (int*)d_ws;
        int* blockbase = blocksums + 64;
        int* tileScan  = blockbase + 64;
        int* offs      = tileScan + NSC;
        int* ssrc      = offs + NN + 1;
        ushort_t* xh   = (ushort_t*)((char*)d_ws + head_b);
        ushort_t* Wt   = (ushort_t*)((char*)d_ws + head_b + xh_b);
        int*    tileHistT = ssrc;                     // alias (NSC <= NE)
        uint_t* coarse    = (uint_t*)d_out;           // alias (NE <= out elems)

        k_setup<<<PREP_BLKS + CONVW_BLKS + NT, 256, 0, stream>>>(x, xh, W, Wt, dst, tileHistT);
        scan_partial<<<NBS, 256, 0, stream>>>(tileHistT, tileScan, blocksums, NSC);
        scan_blocksums<<<1, 64, 0, stream>>>(blocksums, blockbase, NBS);
        p3_scatter<<<NT, 256, 0, stream>>>(dst, src, tileScan, blockbase, coarse);
        p4_build<<<BUK, 256, 0, stream>>>(coarse, tileScan, blockbase, offs, ssrc);
        node_min_v2<<<NN / 4, 256, 0, stream>>>(offs, ssrc, xh);
        gemm_mfma<<<(NN + GM - 1) / GM, 256, 0, stream>>>(xh, Wt, b, out);
    } else {
        int n = NN * C;
        init_neginf<<<(n + 255) / 256, 256, 0, stream>>>(out, n);
        long threads = (long)NE * 32;
        edge_max<<<(int)((threads + 255) / 256), 256, 0, stream>>>(x, src, dst, out);
        gemm_relu<<<(NN + TN - 1) / TN, 256, 0, stream>>>(x, W, b, out);
    }
}